// Round 1
// baseline (7682.311 us; speedup 1.0000x reference)
//
#include <hip/hip_runtime.h>
#include <math.h>

// ---------------------------------------------------------------------------
// EdgeCorrGNN: 4x GCNConv(+relu) + Linear(256,1), fp32 throughout.
// Graph normalization (deg/dinv/norm) computed once, reused for all layers.
// ---------------------------------------------------------------------------

__global__ __launch_bounds__(256) void k_init_deg(float* __restrict__ deg, int n) {
    int i = blockIdx.x * 256 + threadIdx.x;
    if (i < n) deg[i] = 1.0f;  // self-loop weight folded in
}

__global__ __launch_bounds__(256) void k_scatter_deg(const int* __restrict__ dst,
                                                     const float* __restrict__ w,
                                                     float* __restrict__ deg, int e) {
    int i = blockIdx.x * 256 + threadIdx.x;
    if (i < e) atomicAdd(&deg[dst[i]], w[i]);
}

__global__ __launch_bounds__(256) void k_dinv(float* __restrict__ deg, int n) {
    int i = blockIdx.x * 256 + threadIdx.x;
    if (i < n) {
        float d = deg[i];
        deg[i] = d > 0.0f ? 1.0f / sqrtf(d) : 0.0f;  // in-place deg -> dinv
    }
}

__global__ __launch_bounds__(256) void k_norm(const int* __restrict__ src,
                                              const int* __restrict__ dst,
                                              const float* __restrict__ w,
                                              const float* __restrict__ dinv,
                                              float* __restrict__ norm, int e) {
    int i = blockIdx.x * 256 + threadIdx.x;
    if (i < e) norm[i] = dinv[src[i]] * w[i] * dinv[dst[i]];
}

// ---------------------------------------------------------------------------
// fp32 GEMM: C[M,N] = A[M,K] @ B[K,N].  64x64 tile, BK=16, 256 thr, 4x4 micro.
// K % 16 == 0, N % 64 == 0 guaranteed by problem dims; M guarded.
// ---------------------------------------------------------------------------
__global__ __launch_bounds__(256) void gemm64(const float* __restrict__ A,
                                              const float* __restrict__ B,
                                              float* __restrict__ C,
                                              int M, int K, int N) {
    __shared__ float As[16][65];                 // padded: transposed scalar stores
    __shared__ __align__(16) float Bs[16][64];

    int tid = threadIdx.x;
    int tx = tid & 15, ty = tid >> 4;
    int row0 = blockIdx.x * 64;
    int col0 = blockIdx.y * 64;

    int ar = tid >> 2;          // 0..63  (A tile row)
    int ak = (tid & 3) * 4;     // 0,4,8,12 (A tile k offset, float4)
    int br = tid >> 4;          // 0..15  (B tile row)
    int bc = (tid & 15) * 4;    // 0..60  (B tile col, float4)

    float acc[4][4] = {};

    for (int k0 = 0; k0 < K; k0 += 16) {
        float4 av = make_float4(0.f, 0.f, 0.f, 0.f);
        int arow = row0 + ar;
        if (arow < M) av = *(const float4*)(A + (size_t)arow * K + k0 + ak);
        As[ak + 0][ar] = av.x;
        As[ak + 1][ar] = av.y;
        As[ak + 2][ar] = av.z;
        As[ak + 3][ar] = av.w;

        float4 bv = *(const float4*)(B + (size_t)(k0 + br) * N + col0 + bc);
        *(float4*)&Bs[br][bc] = bv;

        __syncthreads();
#pragma unroll
        for (int kk = 0; kk < 16; ++kk) {
            float a0 = As[kk][ty * 4 + 0];
            float a1 = As[kk][ty * 4 + 1];
            float a2 = As[kk][ty * 4 + 2];
            float a3 = As[kk][ty * 4 + 3];
            float4 b4 = *(const float4*)&Bs[kk][tx * 4];
            acc[0][0] += a0 * b4.x; acc[0][1] += a0 * b4.y; acc[0][2] += a0 * b4.z; acc[0][3] += a0 * b4.w;
            acc[1][0] += a1 * b4.x; acc[1][1] += a1 * b4.y; acc[1][2] += a1 * b4.z; acc[1][3] += a1 * b4.w;
            acc[2][0] += a2 * b4.x; acc[2][1] += a2 * b4.y; acc[2][2] += a2 * b4.z; acc[2][3] += a2 * b4.w;
            acc[3][0] += a3 * b4.x; acc[3][1] += a3 * b4.y; acc[3][2] += a3 * b4.z; acc[3][3] += a3 * b4.w;
        }
        __syncthreads();
    }

#pragma unroll
    for (int i = 0; i < 4; ++i) {
        int row = row0 + ty * 4 + i;
        if (row < M) {
#pragma unroll
            for (int j = 0; j < 4; ++j) {
                C[(size_t)row * N + col0 + tx * 4 + j] = acc[i][j];
            }
        }
    }
}

// O[i,:] = dinv[i]^2 * H[i,:]   (self-loop contribution initializes the output)
__global__ __launch_bounds__(256) void k_self_init(const float* __restrict__ H,
                                                   const float* __restrict__ dinv,
                                                   float* __restrict__ O,
                                                   int n, int fout, int shift) {
    long gid = (long)blockIdx.x * 256 + threadIdx.x;
    int chunks = fout >> 2;
    if (gid >= (long)n * chunks) return;
    int i = (int)(gid >> shift);
    int c = (int)(gid & (chunks - 1));
    float di = dinv[i];
    float s = di * di;
    float4 hv = *(const float4*)(H + (size_t)i * fout + c * 4);
    float4 ov;
    ov.x = hv.x * s; ov.y = hv.y * s; ov.z = hv.z * s; ov.w = hv.w * s;
    *(float4*)(O + (size_t)i * fout + c * 4) = ov;
}

// O[dst,:] += norm_e * H[src,:]
__global__ __launch_bounds__(256) void k_edge_scatter(const int* __restrict__ src,
                                                      const int* __restrict__ dst,
                                                      const float* __restrict__ norm,
                                                      const float* __restrict__ H,
                                                      float* __restrict__ O,
                                                      int e, int fout, int shift) {
    long gid = (long)blockIdx.x * 256 + threadIdx.x;
    int chunks = fout >> 2;
    if (gid >= (long)e * chunks) return;
    int ei = (int)(gid >> shift);
    int c = (int)(gid & (chunks - 1));
    int s = src[ei];
    int d = dst[ei];
    float nv = norm[ei];
    float4 hv = *(const float4*)(H + (size_t)s * fout + c * 4);
    float* op = O + (size_t)d * fout + c * 4;
    atomicAdd(op + 0, hv.x * nv);
    atomicAdd(op + 1, hv.y * nv);
    atomicAdd(op + 2, hv.z * nv);
    atomicAdd(op + 3, hv.w * nv);
}

// O = relu(O + b)
__global__ __launch_bounds__(256) void k_bias_relu(float* __restrict__ O,
                                                   const float* __restrict__ b,
                                                   int n, int fout, int shift) {
    long gid = (long)blockIdx.x * 256 + threadIdx.x;
    int chunks = fout >> 2;
    if (gid >= (long)n * chunks) return;
    int i = (int)(gid >> shift);
    int c = (int)(gid & (chunks - 1));
    float4 bv = *(const float4*)(b + c * 4);
    float4 v = *(const float4*)(O + (size_t)i * fout + c * 4);
    v.x = fmaxf(v.x + bv.x, 0.f);
    v.y = fmaxf(v.y + bv.y, 0.f);
    v.z = fmaxf(v.z + bv.z, 0.f);
    v.w = fmaxf(v.w + bv.w, 0.f);
    *(float4*)(O + (size_t)i * fout + c * 4) = v;
}

// out[i] = dot(H[i, 0:256], Wf[:,0]) + bf   -- one wave per node
__global__ __launch_bounds__(256) void k_final_dot(const float* __restrict__ H,
                                                   const float* __restrict__ Wf,
                                                   const float* __restrict__ bf,
                                                   float* __restrict__ out, int n) {
    int wave = (int)((blockIdx.x * 256 + threadIdx.x) >> 6);
    int lane = threadIdx.x & 63;
    if (wave >= n) return;
    float s = 0.f;
#pragma unroll
    for (int j = 0; j < 4; ++j)
        s += H[(size_t)wave * 256 + j * 64 + lane] * Wf[j * 64 + lane];
#pragma unroll
    for (int off = 32; off > 0; off >>= 1) s += __shfl_down(s, off);
    if (lane == 0) out[wave] = s + bf[0];
}

// ---------------------------------------------------------------------------

extern "C" void kernel_launch(void* const* d_in, const int* in_sizes, int n_in,
                              void* d_out, int out_size, void* d_ws, size_t ws_size,
                              hipStream_t stream) {
    const float* x    = (const float*)d_in[0];
    const int*   eidx = (const int*)d_in[1];
    const float* eatt = (const float*)d_in[2];
    const float* W[4] = {(const float*)d_in[3], (const float*)d_in[5],
                         (const float*)d_in[7], (const float*)d_in[9]};
    const float* B[4] = {(const float*)d_in[4], (const float*)d_in[6],
                         (const float*)d_in[8], (const float*)d_in[10]};
    const float* Wf = (const float*)d_in[11];
    const float* bf = (const float*)d_in[12];

    const int NN = in_sizes[0] / 128;   // 50000
    const int NE = in_sizes[2];         // 800000
    const int* src = eidx;              // edge_index[0]
    const int* dst = eidx + NE;         // edge_index[1]

    const int fin[4]  = {128, 64, 128, 256};
    const int fout[4] = {64, 128, 256, 256};

    // workspace layout (all fp32)
    float* ws   = (float*)d_ws;
    float* dinv = ws;                                   // N (deg -> dinv in place)
    float* norm = ws + ((NN + 63) & ~63);               // E
    float* bufA = norm + ((NE + 63) & ~63);             // N*256
    float* bufB = bufA + (size_t)NN * 256;              // N*256

    // --- graph normalization (once) ---
    k_init_deg<<<(NN + 255) / 256, 256, 0, stream>>>(dinv, NN);
    k_scatter_deg<<<(NE + 255) / 256, 256, 0, stream>>>(dst, eatt, dinv, NE);
    k_dinv<<<(NN + 255) / 256, 256, 0, stream>>>(dinv, NN);
    k_norm<<<(NE + 255) / 256, 256, 0, stream>>>(src, dst, eatt, dinv, norm, NE);

    // --- 4 GCN layers: h(bufA or x) -> GEMM -> H(bufB) -> aggregate -> bufA ---
    const float* h = x;
    for (int l = 0; l < 4; ++l) {
        int fi = fin[l], fo = fout[l];
        dim3 g((NN + 63) / 64, fo / 64);
        gemm64<<<g, 256, 0, stream>>>(h, W[l], bufB, NN, fi, fo);

        int chunks = fo >> 2;
        int shift = (fo == 64) ? 4 : (fo == 128) ? 5 : 6;
        long ntot = (long)NN * chunks;
        long etot = (long)NE * chunks;
        k_self_init<<<(int)((ntot + 255) / 256), 256, 0, stream>>>(bufB, dinv, bufA, NN, fo, shift);
        k_edge_scatter<<<(int)((etot + 255) / 256), 256, 0, stream>>>(src, dst, norm, bufB, bufA, NE, fo, shift);
        k_bias_relu<<<(int)((ntot + 255) / 256), 256, 0, stream>>>(bufA, B[l], NN, fo, shift);
        h = bufA;
    }

    // --- final linear (256 -> 1) ---
    k_final_dot<<<(NN * 64 + 255) / 256, 256, 0, stream>>>(bufA, Wf, bf, (float*)d_out, NN);
}

// Round 2
// 933.528 us; speedup vs baseline: 8.2293x; 8.2293x over previous
//
#include <hip/hip_runtime.h>
#include <math.h>

// ---------------------------------------------------------------------------
// EdgeCorrGNN: 4x GCNConv(+relu) + Linear(256,1), fp32.
// R2: atomic scatter-add replaced by CSR build (once) + register gather.
// ---------------------------------------------------------------------------

__global__ __launch_bounds__(256) void k_init(float* __restrict__ deg,
                                              int* __restrict__ cnt, int n) {
    int i = blockIdx.x * 256 + threadIdx.x;
    if (i < n) { deg[i] = 1.0f; cnt[i] = 0; }  // self-loop weight folded into deg
}

__global__ __launch_bounds__(256) void k_count_deg(const int* __restrict__ dst,
                                                   const float* __restrict__ w,
                                                   float* __restrict__ deg,
                                                   int* __restrict__ cnt, int e) {
    int i = blockIdx.x * 256 + threadIdx.x;
    if (i < e) {
        int d = dst[i];
        atomicAdd(&deg[d], w[i]);
        atomicAdd(&cnt[d], 1);
    }
}

__global__ __launch_bounds__(256) void k_dinv(float* __restrict__ deg, int n) {
    int i = blockIdx.x * 256 + threadIdx.x;
    if (i < n) {
        float d = deg[i];
        deg[i] = d > 0.0f ? rsqrtf(d) : 0.0f;  // in-place deg -> dinv
    }
}

// single-block exclusive scan of cnt[0..n) -> row_ptr[0..n]; zeroes cursor.
__global__ __launch_bounds__(1024) void k_scan(const int* __restrict__ cnt,
                                               int* __restrict__ row_ptr,
                                               int* __restrict__ cursor, int n) {
    __shared__ int sp[1024];
    int tid = threadIdx.x;
    int per = (n + 1023) >> 10;
    int start = tid * per;
    int end = min(start + per, n);
    int s = 0;
    for (int i = start; i < end; ++i) s += cnt[i];
    sp[tid] = s;
    __syncthreads();
    for (int d = 1; d < 1024; d <<= 1) {
        int v = (tid >= d) ? sp[tid - d] : 0;
        __syncthreads();
        sp[tid] += v;
        __syncthreads();
    }
    int off = (tid == 0) ? 0 : sp[tid - 1];
    for (int i = start; i < end; ++i) {
        row_ptr[i] = off;
        cursor[i] = 0;
        off += cnt[i];
    }
    if (start < n && end == n) row_ptr[n] = off;
}

// csr[slot] = (src, norm) for each edge, grouped by dst.
__global__ __launch_bounds__(256) void k_fill(const int* __restrict__ src,
                                              const int* __restrict__ dst,
                                              const float* __restrict__ w,
                                              const float* __restrict__ dinv,
                                              const int* __restrict__ row_ptr,
                                              int* __restrict__ cursor,
                                              float2* __restrict__ csr, int e) {
    int i = blockIdx.x * 256 + threadIdx.x;
    if (i < e) {
        int d = dst[i], s = src[i];
        float nv = dinv[s] * w[i] * dinv[d];
        int slot = row_ptr[d] + atomicAdd(&cursor[d], 1);
        csr[slot] = make_float2(__int_as_float(s), nv);
    }
}

// ---------------------------------------------------------------------------
// fp32 GEMM: C[M,N] = A[M,K] @ B[K,N].  64x64 tile, BK=16, 256 thr, 4x4 micro.
// ---------------------------------------------------------------------------
__global__ __launch_bounds__(256) void gemm64(const float* __restrict__ A,
                                              const float* __restrict__ B,
                                              float* __restrict__ C,
                                              int M, int K, int N) {
    __shared__ float As[16][65];
    __shared__ __align__(16) float Bs[16][64];

    int tid = threadIdx.x;
    int tx = tid & 15, ty = tid >> 4;
    int row0 = blockIdx.x * 64;
    int col0 = blockIdx.y * 64;

    int ar = tid >> 2;
    int ak = (tid & 3) * 4;
    int br = tid >> 4;
    int bc = (tid & 15) * 4;

    float acc[4][4] = {};

    for (int k0 = 0; k0 < K; k0 += 16) {
        float4 av = make_float4(0.f, 0.f, 0.f, 0.f);
        int arow = row0 + ar;
        if (arow < M) av = *(const float4*)(A + (size_t)arow * K + k0 + ak);
        As[ak + 0][ar] = av.x;
        As[ak + 1][ar] = av.y;
        As[ak + 2][ar] = av.z;
        As[ak + 3][ar] = av.w;

        float4 bv = *(const float4*)(B + (size_t)(k0 + br) * N + col0 + bc);
        *(float4*)&Bs[br][bc] = bv;

        __syncthreads();
#pragma unroll
        for (int kk = 0; kk < 16; ++kk) {
            float a0 = As[kk][ty * 4 + 0];
            float a1 = As[kk][ty * 4 + 1];
            float a2 = As[kk][ty * 4 + 2];
            float a3 = As[kk][ty * 4 + 3];
            float4 b4 = *(const float4*)&Bs[kk][tx * 4];
            acc[0][0] += a0 * b4.x; acc[0][1] += a0 * b4.y; acc[0][2] += a0 * b4.z; acc[0][3] += a0 * b4.w;
            acc[1][0] += a1 * b4.x; acc[1][1] += a1 * b4.y; acc[1][2] += a1 * b4.z; acc[1][3] += a1 * b4.w;
            acc[2][0] += a2 * b4.x; acc[2][1] += a2 * b4.y; acc[2][2] += a2 * b4.z; acc[2][3] += a2 * b4.w;
            acc[3][0] += a3 * b4.x; acc[3][1] += a3 * b4.y; acc[3][2] += a3 * b4.z; acc[3][3] += a3 * b4.w;
        }
        __syncthreads();
    }

#pragma unroll
    for (int i = 0; i < 4; ++i) {
        int row = row0 + ty * 4 + i;
        if (row < M) {
#pragma unroll
            for (int j = 0; j < 4; ++j) {
                C[(size_t)row * N + col0 + tx * 4 + j] = acc[i][j];
            }
        }
    }
}

// ---------------------------------------------------------------------------
// Gather aggregation, fused self-loop + bias + relu.
// One wave per (node, 64-col segment): O[i,col] = relu(dinv[i]^2*H[i,col]
//   + sum_e norm_e * H[src_e,col] + b[col])
// shift = log2(waves per node) = log2(fo/64).
// ---------------------------------------------------------------------------
__global__ __launch_bounds__(256) void k_gather(const int* __restrict__ row_ptr,
                                                const float2* __restrict__ csr,
                                                const float* __restrict__ H,
                                                const float* __restrict__ dinv,
                                                const float* __restrict__ b,
                                                float* __restrict__ O,
                                                int n, int fo, int shift) {
    int wave = blockIdx.x * 4 + (threadIdx.x >> 6);
    int lane = threadIdx.x & 63;
    int node = wave >> shift;
    if (node >= n) return;
    int col = ((wave & ((1 << shift) - 1)) << 6) + lane;

    float di = dinv[node];
    float acc = di * di * H[(size_t)node * fo + col];

    int e = row_ptr[node];
    int e1 = row_ptr[node + 1];
    for (; e + 1 < e1; e += 2) {
        float2 c0 = csr[e];
        float2 c1 = csr[e + 1];
        int s0 = __float_as_int(c0.x);
        int s1 = __float_as_int(c1.x);
        float h0 = H[(size_t)s0 * fo + col];
        float h1 = H[(size_t)s1 * fo + col];
        acc += c0.y * h0;
        acc += c1.y * h1;
    }
    if (e < e1) {
        float2 c0 = csr[e];
        acc += c0.y * H[(size_t)__float_as_int(c0.x) * fo + col];
    }

    acc += b[col];
    O[(size_t)node * fo + col] = fmaxf(acc, 0.f);
}

// out[i] = dot(H[i, 0:256], Wf[:,0]) + bf   -- one wave per node
__global__ __launch_bounds__(256) void k_final_dot(const float* __restrict__ H,
                                                   const float* __restrict__ Wf,
                                                   const float* __restrict__ bf,
                                                   float* __restrict__ out, int n) {
    int wave = (int)((blockIdx.x * 256 + threadIdx.x) >> 6);
    int lane = threadIdx.x & 63;
    if (wave >= n) return;
    float s = 0.f;
#pragma unroll
    for (int j = 0; j < 4; ++j)
        s += H[(size_t)wave * 256 + j * 64 + lane] * Wf[j * 64 + lane];
#pragma unroll
    for (int off = 32; off > 0; off >>= 1) s += __shfl_down(s, off);
    if (lane == 0) out[wave] = s + bf[0];
}

// ---------------------------------------------------------------------------

extern "C" void kernel_launch(void* const* d_in, const int* in_sizes, int n_in,
                              void* d_out, int out_size, void* d_ws, size_t ws_size,
                              hipStream_t stream) {
    const float* x    = (const float*)d_in[0];
    const int*   eidx = (const int*)d_in[1];
    const float* eatt = (const float*)d_in[2];
    const float* W[4] = {(const float*)d_in[3], (const float*)d_in[5],
                         (const float*)d_in[7], (const float*)d_in[9]};
    const float* B[4] = {(const float*)d_in[4], (const float*)d_in[6],
                         (const float*)d_in[8], (const float*)d_in[10]};
    const float* Wf = (const float*)d_in[11];
    const float* bf = (const float*)d_in[12];

    const int NN = in_sizes[0] / 128;   // 50000
    const int NE = in_sizes[2];         // 800000
    const int* src = eidx;              // edge_index[0]
    const int* dst = eidx + NE;         // edge_index[1]

    const int fin[4]  = {128, 64, 128, 256};
    const int fout[4] = {64, 128, 256, 256};

    // workspace layout
    const int Na = (NN + 64) & ~63;     // padded N (+1 slack for row_ptr)
    float* ws      = (float*)d_ws;
    float* dinv    = ws;                        // N floats (deg -> dinv in place)
    int*   row_ptr = (int*)(ws + Na);           // N+1 ints
    int*   cnt     = row_ptr + Na;              // N ints (count, then cursor)
    float2* csr    = (float2*)(cnt + Na);       // E float2 (src, norm), dst-grouped
    float* bufA    = (float*)(csr + NE);        // N*256
    float* bufB    = bufA + (size_t)NN * 256;   // N*256

    // --- graph preprocessing (CSR + normalization) ---
    k_init<<<(NN + 255) / 256, 256, 0, stream>>>(dinv, cnt, NN);
    k_count_deg<<<(NE + 255) / 256, 256, 0, stream>>>(dst, eatt, dinv, cnt, NE);
    k_dinv<<<(NN + 255) / 256, 256, 0, stream>>>(dinv, NN);
    k_scan<<<1, 1024, 0, stream>>>(cnt, row_ptr, cnt, NN);
    k_fill<<<(NE + 255) / 256, 256, 0, stream>>>(src, dst, eatt, dinv, row_ptr, cnt, csr, NE);

    // --- 4 GCN layers ---
    const float* h = x;
    for (int l = 0; l < 4; ++l) {
        int fi = fin[l], fo = fout[l];
        dim3 g((NN + 63) / 64, fo / 64);
        gemm64<<<g, 256, 0, stream>>>(h, W[l], bufB, NN, fi, fo);

        int wpn = fo >> 6;                      // waves per node (1,2,4)
        int shift = (fo == 64) ? 0 : (fo == 128) ? 1 : 2;
        int waves = NN * wpn;
        k_gather<<<(waves + 3) / 4, 256, 0, stream>>>(row_ptr, csr, bufB, dinv,
                                                      B[l], bufA, NN, fo, shift);
        h = bufA;
    }

    // --- final linear (256 -> 1) ---
    k_final_dot<<<(NN * 64 + 255) / 256, 256, 0, stream>>>(bufA, Wf, bf, (float*)d_out, NN);
}

// Round 3
// 882.307 us; speedup vs baseline: 8.7071x; 1.0581x over previous
//
#include <hip/hip_runtime.h>
#include <math.h>

// ---------------------------------------------------------------------------
// EdgeCorrGNN: 4x GCNConv(+relu) + Linear(256,1), fp32.
// R3: aggregate at min(fin,fout) per layer; fused L4-gather+final-dot;
//     unroll-4 gather MLP; 128x128 GEMM with fused bias+relu.
// ---------------------------------------------------------------------------

__global__ __launch_bounds__(256) void k_init(float* __restrict__ deg,
                                              int* __restrict__ cnt, int n) {
    int i = blockIdx.x * 256 + threadIdx.x;
    if (i < n) { deg[i] = 1.0f; cnt[i] = 0; }  // self-loop weight folded into deg
}

__global__ __launch_bounds__(256) void k_count_deg(const int* __restrict__ dst,
                                                   const float* __restrict__ w,
                                                   float* __restrict__ deg,
                                                   int* __restrict__ cnt, int e) {
    int i = blockIdx.x * 256 + threadIdx.x;
    if (i < e) {
        int d = dst[i];
        atomicAdd(&deg[d], w[i]);
        atomicAdd(&cnt[d], 1);
    }
}

__global__ __launch_bounds__(256) void k_dinv(float* __restrict__ deg, int n) {
    int i = blockIdx.x * 256 + threadIdx.x;
    if (i < n) {
        float d = deg[i];
        deg[i] = d > 0.0f ? rsqrtf(d) : 0.0f;  // in-place deg -> dinv
    }
}

// single-block exclusive scan of cnt[0..n) -> row_ptr[0..n]; zeroes cursor.
__global__ __launch_bounds__(1024) void k_scan(const int* __restrict__ cnt,
                                               int* __restrict__ row_ptr,
                                               int* __restrict__ cursor, int n) {
    __shared__ int sp[1024];
    int tid = threadIdx.x;
    int per = (n + 1023) >> 10;
    int start = tid * per;
    int end = min(start + per, n);
    int s = 0;
    for (int i = start; i < end; ++i) s += cnt[i];
    sp[tid] = s;
    __syncthreads();
    for (int d = 1; d < 1024; d <<= 1) {
        int v = (tid >= d) ? sp[tid - d] : 0;
        __syncthreads();
        sp[tid] += v;
        __syncthreads();
    }
    int off = (tid == 0) ? 0 : sp[tid - 1];
    for (int i = start; i < end; ++i) {
        row_ptr[i] = off;
        cursor[i] = 0;
        off += cnt[i];
    }
    if (start < n && end == n) row_ptr[n] = off;
}

// csr[slot] = (src, norm) for each edge, grouped by dst.
__global__ __launch_bounds__(256) void k_fill(const int* __restrict__ src,
                                              const int* __restrict__ dst,
                                              const float* __restrict__ w,
                                              const float* __restrict__ dinv,
                                              const int* __restrict__ row_ptr,
                                              int* __restrict__ cursor,
                                              float2* __restrict__ csr, int e) {
    int i = blockIdx.x * 256 + threadIdx.x;
    if (i < e) {
        int d = dst[i], s = src[i];
        float nv = dinv[s] * w[i] * dinv[d];
        int slot = row_ptr[d] + atomicAdd(&cursor[d], 1);
        csr[slot] = make_float2(__int_as_float(s), nv);
    }
}

// ---------------------------------------------------------------------------
// fp32 GEMM 64-col tile (for N=64): C[M,N]=A@B, 64x64 tile, BK=16, 4x4 micro.
// ---------------------------------------------------------------------------
__global__ __launch_bounds__(256) void gemm64(const float* __restrict__ A,
                                              const float* __restrict__ B,
                                              float* __restrict__ C,
                                              int M, int K, int N) {
    __shared__ float As[16][65];
    __shared__ __align__(16) float Bs[16][64];

    int tid = threadIdx.x;
    int tx = tid & 15, ty = tid >> 4;
    int row0 = blockIdx.x * 64;
    int col0 = blockIdx.y * 64;

    int ar = tid >> 2;
    int ak = (tid & 3) * 4;
    int br = tid >> 4;
    int bc = (tid & 15) * 4;

    float acc[4][4] = {};

    for (int k0 = 0; k0 < K; k0 += 16) {
        float4 av = make_float4(0.f, 0.f, 0.f, 0.f);
        int arow = row0 + ar;
        if (arow < M) av = *(const float4*)(A + (size_t)arow * K + k0 + ak);
        As[ak + 0][ar] = av.x;
        As[ak + 1][ar] = av.y;
        As[ak + 2][ar] = av.z;
        As[ak + 3][ar] = av.w;

        float4 bv = *(const float4*)(B + (size_t)(k0 + br) * N + col0 + bc);
        *(float4*)&Bs[br][bc] = bv;

        __syncthreads();
#pragma unroll
        for (int kk = 0; kk < 16; ++kk) {
            float a0 = As[kk][ty * 4 + 0];
            float a1 = As[kk][ty * 4 + 1];
            float a2 = As[kk][ty * 4 + 2];
            float a3 = As[kk][ty * 4 + 3];
            float4 b4 = *(const float4*)&Bs[kk][tx * 4];
            acc[0][0] += a0 * b4.x; acc[0][1] += a0 * b4.y; acc[0][2] += a0 * b4.z; acc[0][3] += a0 * b4.w;
            acc[1][0] += a1 * b4.x; acc[1][1] += a1 * b4.y; acc[1][2] += a1 * b4.z; acc[1][3] += a1 * b4.w;
            acc[2][0] += a2 * b4.x; acc[2][1] += a2 * b4.y; acc[2][2] += a2 * b4.z; acc[2][3] += a2 * b4.w;
            acc[3][0] += a3 * b4.x; acc[3][1] += a3 * b4.y; acc[3][2] += a3 * b4.z; acc[3][3] += a3 * b4.w;
        }
        __syncthreads();
    }

#pragma unroll
    for (int i = 0; i < 4; ++i) {
        int row = row0 + ty * 4 + i;
        if (row < M) {
#pragma unroll
            for (int j = 0; j < 4; ++j) {
                C[(size_t)row * N + col0 + tx * 4 + j] = acc[i][j];
            }
        }
    }
}

// ---------------------------------------------------------------------------
// fp32 GEMM 128x128 tile, BK=16, 256 thr, 8x8 split micro-tile (2x2 of 4x4).
// Optional fused epilogue: C = relu(A@B + bias).
// Requires N % 128 == 0, K % 16 == 0.
// ---------------------------------------------------------------------------
__device__ __forceinline__ void fma4(float4& c, float a, const float4& b) {
    c.x += a * b.x; c.y += a * b.y; c.z += a * b.z; c.w += a * b.w;
}

template <bool RELU>
__global__ __launch_bounds__(256) void gemm128(const float* __restrict__ A,
                                               const float* __restrict__ B,
                                               const float* __restrict__ bias,
                                               float* __restrict__ C,
                                               int M, int K, int N) {
    __shared__ float As[16][132];   // transposed A tile: As[k][m]
    __shared__ float Bs[16][132];   // Bs[k][n]

    int tid = threadIdx.x;
    int tx = tid & 15, ty = tid >> 4;
    int row0 = blockIdx.x * 128;
    int col0 = blockIdx.y * 128;

    int ar = tid >> 2;          // 0..63
    int ac = (tid & 3) * 4;     // 0,4,8,12
    int br = tid >> 5;          // 0..7
    int bc = (tid & 31) * 4;    // 0..124

    float4 acc[2][2][4] = {};   // [mblk][nblk][mi] -> 4 cols

    for (int k0 = 0; k0 < K; k0 += 16) {
#pragma unroll
        for (int h = 0; h < 2; ++h) {
            int arow = row0 + h * 64 + ar;
            float4 av = make_float4(0.f, 0.f, 0.f, 0.f);
            if (arow < M) av = *(const float4*)(A + (size_t)arow * K + k0 + ac);
            As[ac + 0][h * 64 + ar] = av.x;
            As[ac + 1][h * 64 + ar] = av.y;
            As[ac + 2][h * 64 + ar] = av.z;
            As[ac + 3][h * 64 + ar] = av.w;
        }
#pragma unroll
        for (int h = 0; h < 2; ++h) {
            float4 bv = *(const float4*)(B + (size_t)(k0 + br + h * 8) * N + col0 + bc);
            *(float4*)&Bs[br + h * 8][bc] = bv;
        }
        __syncthreads();
#pragma unroll
        for (int kk = 0; kk < 16; ++kk) {
            float4 a0 = *(const float4*)&As[kk][ty * 4];
            float4 a1 = *(const float4*)&As[kk][64 + ty * 4];
            float4 b0 = *(const float4*)&Bs[kk][tx * 4];
            float4 b1 = *(const float4*)&Bs[kk][64 + tx * 4];
            fma4(acc[0][0][0], a0.x, b0); fma4(acc[0][0][1], a0.y, b0);
            fma4(acc[0][0][2], a0.z, b0); fma4(acc[0][0][3], a0.w, b0);
            fma4(acc[0][1][0], a0.x, b1); fma4(acc[0][1][1], a0.y, b1);
            fma4(acc[0][1][2], a0.z, b1); fma4(acc[0][1][3], a0.w, b1);
            fma4(acc[1][0][0], a1.x, b0); fma4(acc[1][0][1], a1.y, b0);
            fma4(acc[1][0][2], a1.z, b0); fma4(acc[1][0][3], a1.w, b0);
            fma4(acc[1][1][0], a1.x, b1); fma4(acc[1][1][1], a1.y, b1);
            fma4(acc[1][1][2], a1.z, b1); fma4(acc[1][1][3], a1.w, b1);
        }
        __syncthreads();
    }

#pragma unroll
    for (int mb = 0; mb < 2; ++mb) {
#pragma unroll
        for (int mi = 0; mi < 4; ++mi) {
            int row = row0 + mb * 64 + ty * 4 + mi;
            if (row >= M) continue;
#pragma unroll
            for (int nb = 0; nb < 2; ++nb) {
                int col = col0 + nb * 64 + tx * 4;
                float4 v = acc[mb][nb][mi];
                if (RELU) {
                    float4 bv = *(const float4*)(bias + col);
                    v.x = fmaxf(v.x + bv.x, 0.f);
                    v.y = fmaxf(v.y + bv.y, 0.f);
                    v.z = fmaxf(v.z + bv.z, 0.f);
                    v.w = fmaxf(v.w + bv.w, 0.f);
                }
                *(float4*)(C + (size_t)row * N + col) = v;
            }
        }
    }
}

// ---------------------------------------------------------------------------
// Gather aggregation. One wave per (node, 64-col segment).
//   O[i,col] = dinv[i]^2*H[i,col] + sum_e norm_e*H[src_e,col]   (+bias,relu)
// bias == nullptr -> raw aggregate (no bias, no relu).
// ---------------------------------------------------------------------------
__global__ __launch_bounds__(256) void k_gather(const int* __restrict__ row_ptr,
                                                const float2* __restrict__ csr,
                                                const float* __restrict__ H,
                                                const float* __restrict__ dinv,
                                                const float* __restrict__ b,
                                                float* __restrict__ O,
                                                int n, int fo, int shift) {
    int wave = blockIdx.x * 4 + (threadIdx.x >> 6);
    int lane = threadIdx.x & 63;
    int node = wave >> shift;
    if (node >= n) return;
    int col = ((wave & ((1 << shift) - 1)) << 6) + lane;

    float di = dinv[node];
    float acc = di * di * H[(size_t)node * fo + col];

    int e = row_ptr[node];
    int e1 = row_ptr[node + 1];
    for (; e + 3 < e1; e += 4) {
        float2 c0 = csr[e + 0];
        float2 c1 = csr[e + 1];
        float2 c2 = csr[e + 2];
        float2 c3 = csr[e + 3];
        float h0 = H[(size_t)__float_as_int(c0.x) * fo + col];
        float h1 = H[(size_t)__float_as_int(c1.x) * fo + col];
        float h2 = H[(size_t)__float_as_int(c2.x) * fo + col];
        float h3 = H[(size_t)__float_as_int(c3.x) * fo + col];
        acc += c0.y * h0;
        acc += c1.y * h1;
        acc += c2.y * h2;
        acc += c3.y * h3;
    }
    for (; e < e1; ++e) {
        float2 c = csr[e];
        acc += c.y * H[(size_t)__float_as_int(c.x) * fo + col];
    }

    if (b != nullptr) {
        acc += b[col];
        acc = fmaxf(acc, 0.f);
    }
    O[(size_t)node * fo + col] = acc;
}

// ---------------------------------------------------------------------------
// Fused layer-4 gather + bias + relu + final Linear(256,1).
// One block (4 waves) per node; wave w owns cols [w*64, w*64+64).
//   row[col] = relu(dinv^2*H[node,col] + sum norm*H[src,col] + b4[col])
//   out[node] = dot(row, Wf) + bf
// ---------------------------------------------------------------------------
__global__ __launch_bounds__(256) void k_gather_final(const int* __restrict__ row_ptr,
                                                      const float2* __restrict__ csr,
                                                      const float* __restrict__ H,
                                                      const float* __restrict__ dinv,
                                                      const float* __restrict__ b4,
                                                      const float* __restrict__ Wf,
                                                      const float* __restrict__ bf,
                                                      float* __restrict__ out, int n) {
    __shared__ float red[4];
    int node = blockIdx.x;
    if (node >= n) return;
    int w = threadIdx.x >> 6;
    int lane = threadIdx.x & 63;
    int col = (w << 6) + lane;

    float di = dinv[node];
    float acc = di * di * H[(size_t)node * 256 + col];

    int e = row_ptr[node];
    int e1 = row_ptr[node + 1];
    for (; e + 3 < e1; e += 4) {
        float2 c0 = csr[e + 0];
        float2 c1 = csr[e + 1];
        float2 c2 = csr[e + 2];
        float2 c3 = csr[e + 3];
        float h0 = H[(size_t)__float_as_int(c0.x) * 256 + col];
        float h1 = H[(size_t)__float_as_int(c1.x) * 256 + col];
        float h2 = H[(size_t)__float_as_int(c2.x) * 256 + col];
        float h3 = H[(size_t)__float_as_int(c3.x) * 256 + col];
        acc += c0.y * h0;
        acc += c1.y * h1;
        acc += c2.y * h2;
        acc += c3.y * h3;
    }
    for (; e < e1; ++e) {
        float2 c = csr[e];
        acc += c.y * H[(size_t)__float_as_int(c.x) * 256 + col];
    }

    float v = fmaxf(acc + b4[col], 0.f) * Wf[col];
#pragma unroll
    for (int off = 32; off > 0; off >>= 1) v += __shfl_down(v, off);
    if (lane == 0) red[w] = v;
    __syncthreads();
    if (threadIdx.x == 0)
        out[node] = red[0] + red[1] + red[2] + red[3] + bf[0];
}

// ---------------------------------------------------------------------------

extern "C" void kernel_launch(void* const* d_in, const int* in_sizes, int n_in,
                              void* d_out, int out_size, void* d_ws, size_t ws_size,
                              hipStream_t stream) {
    const float* x    = (const float*)d_in[0];
    const int*   eidx = (const int*)d_in[1];
    const float* eatt = (const float*)d_in[2];
    const float* W1 = (const float*)d_in[3];
    const float* b1 = (const float*)d_in[4];
    const float* W2 = (const float*)d_in[5];
    const float* b2 = (const float*)d_in[6];
    const float* W3 = (const float*)d_in[7];
    const float* b3 = (const float*)d_in[8];
    const float* W4 = (const float*)d_in[9];
    const float* b4 = (const float*)d_in[10];
    const float* Wf = (const float*)d_in[11];
    const float* bf = (const float*)d_in[12];

    const int NN = in_sizes[0] / 128;   // 50000
    const int NE = in_sizes[2];         // 800000
    const int* src = eidx;              // edge_index[0]
    const int* dst = eidx + NE;         // edge_index[1]

    // workspace layout
    const int Na = (NN + 64) & ~63;
    float* ws      = (float*)d_ws;
    float* dinv    = ws;                        // N floats
    int*   row_ptr = (int*)(ws + Na);           // N+1 ints
    int*   cnt     = row_ptr + Na;              // N ints (count, then cursor)
    float2* csr    = (float2*)(cnt + Na);       // E float2 (src, norm)
    float* bufA    = (float*)(csr + NE);        // N*256
    float* bufB    = bufA + (size_t)NN * 256;   // N*256

    // --- graph preprocessing ---
    k_init<<<(NN + 255) / 256, 256, 0, stream>>>(dinv, cnt, NN);
    k_count_deg<<<(NE + 255) / 256, 256, 0, stream>>>(dst, eatt, dinv, cnt, NE);
    k_dinv<<<(NN + 255) / 256, 256, 0, stream>>>(dinv, NN);
    k_scan<<<1, 1024, 0, stream>>>(cnt, row_ptr, cnt, NN);
    k_fill<<<(NE + 255) / 256, 256, 0, stream>>>(src, dst, eatt, dinv, row_ptr, cnt, csr, NE);

    int gw = (NN + 3) / 4;  // blocks for 1-wave-per-node gathers

    // --- L1 (128->64), aggregate AFTER: H1 = x@W1; h1 = relu(gather(H1)+b1)
    {
        dim3 g((NN + 63) / 64, 1);
        gemm64<<<g, 256, 0, stream>>>(x, W1, bufB, NN, 128, 64);
        k_gather<<<gw, 256, 0, stream>>>(row_ptr, csr, bufB, dinv, b1, bufA, NN, 64, 0);
    }
    // --- L2 (64->128), aggregate BEFORE: g2 = gather(h1); h2 = relu(g2@W2+b2)
    {
        k_gather<<<gw, 256, 0, stream>>>(row_ptr, csr, bufA, dinv, nullptr, bufB, NN, 64, 0);
        dim3 g((NN + 127) / 128, 1);
        gemm128<true><<<g, 256, 0, stream>>>(bufB, W2, b2, bufA, NN, 64, 128);
    }
    // --- L3 (128->256), aggregate BEFORE: g3 = gather(h2); h3 = relu(g3@W3+b3)
    {
        k_gather<<<(NN * 2 + 3) / 4, 256, 0, stream>>>(row_ptr, csr, bufA, dinv, nullptr, bufB, NN, 128, 1);
        dim3 g((NN + 127) / 128, 2);
        gemm128<true><<<g, 256, 0, stream>>>(bufB, W3, b3, bufA, NN, 128, 256);
    }
    // --- L4 (256->256) aggregate AFTER + fused final dot
    {
        dim3 g((NN + 127) / 128, 2);
        gemm128<false><<<g, 256, 0, stream>>>(bufA, W4, nullptr, bufB, NN, 256, 256);
        k_gather_final<<<NN, 256, 0, stream>>>(row_ptr, csr, bufB, dinv, b4, Wf, bf,
                                               (float*)d_out, NN);
    }
}

// Round 4
// 663.864 us; speedup vs baseline: 11.5721x; 1.3290x over previous
//
#include <hip/hip_runtime.h>
#include <math.h>

// ---------------------------------------------------------------------------
// EdgeCorrGNN: 4x GCNConv(+relu) + Linear(256,1).
// R4: GEMMs moved to fp16 MFMA (fp32 accumulate); gathers/preproc unchanged.
// ---------------------------------------------------------------------------

typedef _Float16 half8 __attribute__((ext_vector_type(8)));
typedef float f32x4 __attribute__((ext_vector_type(4)));

__global__ __launch_bounds__(256) void k_init(float* __restrict__ deg,
                                              int* __restrict__ cnt, int n) {
    int i = blockIdx.x * 256 + threadIdx.x;
    if (i < n) { deg[i] = 1.0f; cnt[i] = 0; }  // self-loop weight folded into deg
}

__global__ __launch_bounds__(256) void k_count_deg(const int* __restrict__ dst,
                                                   const float* __restrict__ w,
                                                   float* __restrict__ deg,
                                                   int* __restrict__ cnt, int e) {
    int i = blockIdx.x * 256 + threadIdx.x;
    if (i < e) {
        int d = dst[i];
        atomicAdd(&deg[d], w[i]);
        atomicAdd(&cnt[d], 1);
    }
}

__global__ __launch_bounds__(256) void k_dinv(float* __restrict__ deg, int n) {
    int i = blockIdx.x * 256 + threadIdx.x;
    if (i < n) {
        float d = deg[i];
        deg[i] = d > 0.0f ? rsqrtf(d) : 0.0f;  // in-place deg -> dinv
    }
}

// single-block exclusive scan of cnt[0..n) -> row_ptr[0..n]; zeroes cursor.
__global__ __launch_bounds__(1024) void k_scan(const int* __restrict__ cnt,
                                               int* __restrict__ row_ptr,
                                               int* __restrict__ cursor, int n) {
    __shared__ int sp[1024];
    int tid = threadIdx.x;
    int per = (n + 1023) >> 10;
    int start = tid * per;
    int end = min(start + per, n);
    int s = 0;
    for (int i = start; i < end; ++i) s += cnt[i];
    sp[tid] = s;
    __syncthreads();
    for (int d = 1; d < 1024; d <<= 1) {
        int v = (tid >= d) ? sp[tid - d] : 0;
        __syncthreads();
        sp[tid] += v;
        __syncthreads();
    }
    int off = (tid == 0) ? 0 : sp[tid - 1];
    for (int i = start; i < end; ++i) {
        row_ptr[i] = off;
        cursor[i] = 0;
        off += cnt[i];
    }
    if (start < n && end == n) row_ptr[n] = off;
}

// csr[slot] = (src, norm) for each edge, grouped by dst.
__global__ __launch_bounds__(256) void k_fill(const int* __restrict__ src,
                                              const int* __restrict__ dst,
                                              const float* __restrict__ w,
                                              const float* __restrict__ dinv,
                                              const int* __restrict__ row_ptr,
                                              int* __restrict__ cursor,
                                              float2* __restrict__ csr, int e) {
    int i = blockIdx.x * 256 + threadIdx.x;
    if (i < e) {
        int d = dst[i], s = src[i];
        float nv = dinv[s] * w[i] * dinv[d];
        int slot = row_ptr[d] + atomicAdd(&cursor[d], 1);
        csr[slot] = make_float2(__int_as_float(s), nv);
    }
}

// ---------------------------------------------------------------------------
// fp16-MFMA GEMM: C[M,N] = A[M,K]@B[K,N] (+bias, relu). fp32 in/out.
// BM=128, BN=64, BK=64; 4 waves, each owns 32 rows x 64 cols.
// MFMA 16x16x32_f16; A/B frag: lane l -> elem (l&15, 8*(l>>4)+j) contiguous k;
// C/D: col=lane&15, row=(lane>>4)*4+reg  [m89/m92-verified mapping].
// LDS rows padded to 72 halves (144 B): 2-way bank aliasing only (free).
// Requires K%64==0, N%64==0.
// ---------------------------------------------------------------------------
template <bool RELU>
__global__ __launch_bounds__(256) void gemm_mfma(const float* __restrict__ A,
                                                 const float* __restrict__ B,
                                                 const float* __restrict__ bias,
                                                 float* __restrict__ C,
                                                 int M, int K, int N) {
    constexpr int PK = 72;
    __shared__ _Float16 Asl[128 * PK];
    __shared__ _Float16 Bsl[64 * PK];

    int tid = threadIdx.x;
    int w = tid >> 6, l = tid & 63;
    int row0 = blockIdx.x * 128, col0 = blockIdx.y * 64;
    int wr = w * 32;
    int lr = l & 15, lg = l >> 4;

    int srow = tid >> 1;            // A staging: 0..127
    int skh = (tid & 1) * 32;       // half-row of 32 floats
    int bk = tid >> 4;              // B staging: k 0..15 (+16r)
    int bn = (tid & 15) * 4;        // n group of 4

    f32x4 acc[2][4] = {};

    for (int k0 = 0; k0 < K; k0 += 64) {
        // --- stage A (fp32 -> fp16), 32 elems/thread ---
        const float* ap = A + (size_t)(row0 + srow) * K + k0 + skh;
        bool aok = (row0 + srow) < M;
#pragma unroll
        for (int i = 0; i < 4; ++i) {
            float4 v0 = aok ? *(const float4*)(ap + i * 8 + 0) : make_float4(0.f, 0.f, 0.f, 0.f);
            float4 v1 = aok ? *(const float4*)(ap + i * 8 + 4) : make_float4(0.f, 0.f, 0.f, 0.f);
            half8 h;
            h[0] = (_Float16)v0.x; h[1] = (_Float16)v0.y;
            h[2] = (_Float16)v0.z; h[3] = (_Float16)v0.w;
            h[4] = (_Float16)v1.x; h[5] = (_Float16)v1.y;
            h[6] = (_Float16)v1.z; h[7] = (_Float16)v1.w;
            *(half8*)&Asl[srow * PK + skh + i * 8] = h;
        }
        // --- stage B transposed ([n][k]), 16 elems/thread ---
#pragma unroll
        for (int r = 0; r < 4; ++r) {
            int kk = bk + r * 16;
            float4 wv = *(const float4*)(B + (size_t)(k0 + kk) * N + col0 + bn);
            Bsl[(bn + 0) * PK + kk] = (_Float16)wv.x;
            Bsl[(bn + 1) * PK + kk] = (_Float16)wv.y;
            Bsl[(bn + 2) * PK + kk] = (_Float16)wv.z;
            Bsl[(bn + 3) * PK + kk] = (_Float16)wv.w;
        }
        __syncthreads();

#pragma unroll
        for (int kr = 0; kr < 2; ++kr) {
            half8 af[2], bf[4];
#pragma unroll
            for (int m = 0; m < 2; ++m)
                af[m] = *(half8*)&Asl[(wr + m * 16 + lr) * PK + kr * 32 + lg * 8];
#pragma unroll
            for (int n = 0; n < 4; ++n)
                bf[n] = *(half8*)&Bsl[(n * 16 + lr) * PK + kr * 32 + lg * 8];
#pragma unroll
            for (int m = 0; m < 2; ++m)
#pragma unroll
                for (int n = 0; n < 4; ++n)
                    acc[m][n] = __builtin_amdgcn_mfma_f32_16x16x32_f16(
                        af[m], bf[n], acc[m][n], 0, 0, 0);
        }
        __syncthreads();
    }

#pragma unroll
    for (int m = 0; m < 2; ++m) {
#pragma unroll
        for (int r = 0; r < 4; ++r) {
            int row = row0 + wr + m * 16 + lg * 4 + r;
            if (row >= M) continue;
#pragma unroll
            for (int n = 0; n < 4; ++n) {
                int col = col0 + n * 16 + lr;
                float v = acc[m][n][r];
                if (RELU) v = fmaxf(v + bias[col], 0.f);
                C[(size_t)row * N + col] = v;
            }
        }
    }
}

// ---------------------------------------------------------------------------
// Gather aggregation. One wave per (node, 64-col segment).
//   O[i,col] = dinv[i]^2*H[i,col] + sum_e norm_e*H[src_e,col]   (+bias,relu)
// bias == nullptr -> raw aggregate.
// ---------------------------------------------------------------------------
__global__ __launch_bounds__(256) void k_gather(const int* __restrict__ row_ptr,
                                                const float2* __restrict__ csr,
                                                const float* __restrict__ H,
                                                const float* __restrict__ dinv,
                                                const float* __restrict__ b,
                                                float* __restrict__ O,
                                                int n, int fo, int shift) {
    int wave = blockIdx.x * 4 + (threadIdx.x >> 6);
    int lane = threadIdx.x & 63;
    int node = wave >> shift;
    if (node >= n) return;
    int col = ((wave & ((1 << shift) - 1)) << 6) + lane;

    float di = dinv[node];
    float acc = di * di * H[(size_t)node * fo + col];

    int e = row_ptr[node];
    int e1 = row_ptr[node + 1];
    for (; e + 3 < e1; e += 4) {
        float2 c0 = csr[e + 0];
        float2 c1 = csr[e + 1];
        float2 c2 = csr[e + 2];
        float2 c3 = csr[e + 3];
        float h0 = H[(size_t)__float_as_int(c0.x) * fo + col];
        float h1 = H[(size_t)__float_as_int(c1.x) * fo + col];
        float h2 = H[(size_t)__float_as_int(c2.x) * fo + col];
        float h3 = H[(size_t)__float_as_int(c3.x) * fo + col];
        acc += c0.y * h0;
        acc += c1.y * h1;
        acc += c2.y * h2;
        acc += c3.y * h3;
    }
    for (; e < e1; ++e) {
        float2 c = csr[e];
        acc += c.y * H[(size_t)__float_as_int(c.x) * fo + col];
    }

    if (b != nullptr) {
        acc += b[col];
        acc = fmaxf(acc, 0.f);
    }
    O[(size_t)node * fo + col] = acc;
}

// ---------------------------------------------------------------------------
// Fused layer-4 gather + bias + relu + final Linear(256,1).
// ---------------------------------------------------------------------------
__global__ __launch_bounds__(256) void k_gather_final(const int* __restrict__ row_ptr,
                                                      const float2* __restrict__ csr,
                                                      const float* __restrict__ H,
                                                      const float* __restrict__ dinv,
                                                      const float* __restrict__ b4,
                                                      const float* __restrict__ Wf,
                                                      const float* __restrict__ bf,
                                                      float* __restrict__ out, int n) {
    __shared__ float red[4];
    int node = blockIdx.x;
    if (node >= n) return;
    int w = threadIdx.x >> 6;
    int lane = threadIdx.x & 63;
    int col = (w << 6) + lane;

    float di = dinv[node];
    float acc = di * di * H[(size_t)node * 256 + col];

    int e = row_ptr[node];
    int e1 = row_ptr[node + 1];
    for (; e + 3 < e1; e += 4) {
        float2 c0 = csr[e + 0];
        float2 c1 = csr[e + 1];
        float2 c2 = csr[e + 2];
        float2 c3 = csr[e + 3];
        float h0 = H[(size_t)__float_as_int(c0.x) * 256 + col];
        float h1 = H[(size_t)__float_as_int(c1.x) * 256 + col];
        float h2 = H[(size_t)__float_as_int(c2.x) * 256 + col];
        float h3 = H[(size_t)__float_as_int(c3.x) * 256 + col];
        acc += c0.y * h0;
        acc += c1.y * h1;
        acc += c2.y * h2;
        acc += c3.y * h3;
    }
    for (; e < e1; ++e) {
        float2 c = csr[e];
        acc += c.y * H[(size_t)__float_as_int(c.x) * 256 + col];
    }

    float v = fmaxf(acc + b4[col], 0.f) * Wf[col];
#pragma unroll
    for (int off = 32; off > 0; off >>= 1) v += __shfl_down(v, off);
    if (lane == 0) red[w] = v;
    __syncthreads();
    if (threadIdx.x == 0)
        out[node] = red[0] + red[1] + red[2] + red[3] + bf[0];
}

// ---------------------------------------------------------------------------

extern "C" void kernel_launch(void* const* d_in, const int* in_sizes, int n_in,
                              void* d_out, int out_size, void* d_ws, size_t ws_size,
                              hipStream_t stream) {
    const float* x    = (const float*)d_in[0];
    const int*   eidx = (const int*)d_in[1];
    const float* eatt = (const float*)d_in[2];
    const float* W1 = (const float*)d_in[3];
    const float* b1 = (const float*)d_in[4];
    const float* W2 = (const float*)d_in[5];
    const float* b2 = (const float*)d_in[6];
    const float* W3 = (const float*)d_in[7];
    const float* b3 = (const float*)d_in[8];
    const float* W4 = (const float*)d_in[9];
    const float* b4 = (const float*)d_in[10];
    const float* Wf = (const float*)d_in[11];
    const float* bf = (const float*)d_in[12];

    const int NN = in_sizes[0] / 128;   // 50000
    const int NE = in_sizes[2];         // 800000
    const int* src = eidx;              // edge_index[0]
    const int* dst = eidx + NE;         // edge_index[1]

    // workspace layout
    const int Na = (NN + 64) & ~63;
    float* ws      = (float*)d_ws;
    float* dinv    = ws;                        // N floats
    int*   row_ptr = (int*)(ws + Na);           // N+1 ints
    int*   cnt     = row_ptr + Na;              // N ints (count, then cursor)
    float2* csr    = (float2*)(cnt + Na);       // E float2 (src, norm)
    float* bufA    = (float*)(csr + NE);        // N*256
    float* bufB    = bufA + (size_t)NN * 256;   // N*256

    // --- graph preprocessing ---
    k_init<<<(NN + 255) / 256, 256, 0, stream>>>(dinv, cnt, NN);
    k_count_deg<<<(NE + 255) / 256, 256, 0, stream>>>(dst, eatt, dinv, cnt, NE);
    k_dinv<<<(NN + 255) / 256, 256, 0, stream>>>(dinv, NN);
    k_scan<<<1, 1024, 0, stream>>>(cnt, row_ptr, cnt, NN);
    k_fill<<<(NE + 255) / 256, 256, 0, stream>>>(src, dst, eatt, dinv, row_ptr, cnt, csr, NE);

    int gw = (NN + 3) / 4;
    int gx = (NN + 127) / 128;

    // --- L1 (128->64), aggregate AFTER: H1 = x@W1; h1 = relu(gather(H1)+b1)
    gemm_mfma<false><<<dim3(gx, 1), 256, 0, stream>>>(x, W1, nullptr, bufB, NN, 128, 64);
    k_gather<<<gw, 256, 0, stream>>>(row_ptr, csr, bufB, dinv, b1, bufA, NN, 64, 0);

    // --- L2 (64->128), aggregate BEFORE: g2 = gather(h1); h2 = relu(g2@W2+b2)
    k_gather<<<gw, 256, 0, stream>>>(row_ptr, csr, bufA, dinv, nullptr, bufB, NN, 64, 0);
    gemm_mfma<true><<<dim3(gx, 2), 256, 0, stream>>>(bufB, W2, b2, bufA, NN, 64, 128);

    // --- L3 (128->256), aggregate BEFORE: g3 = gather(h2); h3 = relu(g3@W3+b3)
    k_gather<<<(NN * 2 + 3) / 4, 256, 0, stream>>>(row_ptr, csr, bufA, dinv, nullptr, bufB, NN, 128, 1);
    gemm_mfma<true><<<dim3(gx, 4), 256, 0, stream>>>(bufB, W3, b3, bufA, NN, 128, 256);

    // --- L4 (256->256) aggregate AFTER + fused final dot
    gemm_mfma<false><<<dim3(gx, 4), 256, 0, stream>>>(bufA, W4, nullptr, bufB, NN, 256, 256);
    k_gather_final<<<NN, 256, 0, stream>>>(row_ptr, csr, bufB, dinv, b4, Wf, bf,
                                           (float*)d_out, NN);
}

// Round 5
// 547.872 us; speedup vs baseline: 14.0221x; 1.2117x over previous
//
#include <hip/hip_runtime.h>
#include <math.h>

// ---------------------------------------------------------------------------
// EdgeCorrGNN: 4x GCNConv(+relu) + Linear(256,1).
// R5: fp16 intermediate H buffers everywhere (gather traffic halved);
//     fp16-MFMA GEMMs read fp16 A directly; all accumulation in fp32.
// ---------------------------------------------------------------------------

typedef _Float16 half8 __attribute__((ext_vector_type(8)));
typedef float f32x4 __attribute__((ext_vector_type(4)));

__global__ __launch_bounds__(256) void k_init(float* __restrict__ deg,
                                              int* __restrict__ cnt, int n) {
    int i = blockIdx.x * 256 + threadIdx.x;
    if (i < n) { deg[i] = 1.0f; cnt[i] = 0; }  // self-loop weight folded into deg
}

__global__ __launch_bounds__(256) void k_count_deg(const int* __restrict__ dst,
                                                   const float* __restrict__ w,
                                                   float* __restrict__ deg,
                                                   int* __restrict__ cnt, int e) {
    int i = blockIdx.x * 256 + threadIdx.x;
    if (i < e) {
        int d = dst[i];
        atomicAdd(&deg[d], w[i]);
        atomicAdd(&cnt[d], 1);
    }
}

__global__ __launch_bounds__(256) void k_dinv(float* __restrict__ deg, int n) {
    int i = blockIdx.x * 256 + threadIdx.x;
    if (i < n) {
        float d = deg[i];
        deg[i] = d > 0.0f ? rsqrtf(d) : 0.0f;  // in-place deg -> dinv
    }
}

// single-block exclusive scan of cnt[0..n) -> row_ptr[0..n]; zeroes cursor.
__global__ __launch_bounds__(1024) void k_scan(const int* __restrict__ cnt,
                                               int* __restrict__ row_ptr,
                                               int* __restrict__ cursor, int n) {
    __shared__ int sp[1024];
    int tid = threadIdx.x;
    int per = (n + 1023) >> 10;
    int start = tid * per;
    int end = min(start + per, n);
    int s = 0;
    for (int i = start; i < end; ++i) s += cnt[i];
    sp[tid] = s;
    __syncthreads();
    for (int d = 1; d < 1024; d <<= 1) {
        int v = (tid >= d) ? sp[tid - d] : 0;
        __syncthreads();
        sp[tid] += v;
        __syncthreads();
    }
    int off = (tid == 0) ? 0 : sp[tid - 1];
    for (int i = start; i < end; ++i) {
        row_ptr[i] = off;
        cursor[i] = 0;
        off += cnt[i];
    }
    if (start < n && end == n) row_ptr[n] = off;
}

// csr[slot] = (src, norm) for each edge, grouped by dst.
__global__ __launch_bounds__(256) void k_fill(const int* __restrict__ src,
                                              const int* __restrict__ dst,
                                              const float* __restrict__ w,
                                              const float* __restrict__ dinv,
                                              const int* __restrict__ row_ptr,
                                              int* __restrict__ cursor,
                                              float2* __restrict__ csr, int e) {
    int i = blockIdx.x * 256 + threadIdx.x;
    if (i < e) {
        int d = dst[i], s = src[i];
        float nv = dinv[s] * w[i] * dinv[d];
        int slot = row_ptr[d] + atomicAdd(&cursor[d], 1);
        csr[slot] = make_float2(__int_as_float(s), nv);
    }
}

// ---------------------------------------------------------------------------
// fp16-MFMA GEMM: C[M,N] = A[M,K]@B[K,N] (+bias, relu). A fp32 or fp16;
// B/bias fp32; C fp16.  BM=128, BN=64, BK=64; 4 waves x (32rows x 64cols).
// MFMA 16x16x32_f16; LDS rows padded to 72 halves (2-way aliasing = free).
// Requires K%64==0, N%64==0.
// ---------------------------------------------------------------------------
template <bool RELU, typename TA>
__global__ __launch_bounds__(256) void gemm_mfma(const TA* __restrict__ A,
                                                 const float* __restrict__ B,
                                                 const float* __restrict__ bias,
                                                 _Float16* __restrict__ C,
                                                 int M, int K, int N) {
    constexpr int PK = 72;
    __shared__ _Float16 Asl[128 * PK];
    __shared__ _Float16 Bsl[64 * PK];

    int tid = threadIdx.x;
    int w = tid >> 6, l = tid & 63;
    int row0 = blockIdx.x * 128, col0 = blockIdx.y * 64;
    int wr = w * 32;
    int lr = l & 15, lg = l >> 4;

    int srow = tid >> 1;            // A staging: 0..127
    int skh = (tid & 1) * 32;       // half-row of 32 elems
    int bk = tid >> 4;              // B staging: k 0..15 (+16r)
    int bn = (tid & 15) * 4;        // n group of 4

    f32x4 acc[2][4] = {};

    for (int k0 = 0; k0 < K; k0 += 64) {
        // --- stage A, 32 elems/thread ---
        const TA* ap = A + (size_t)(row0 + srow) * K + k0 + skh;
        bool aok = (row0 + srow) < M;
#pragma unroll
        for (int i = 0; i < 4; ++i) {
            half8 h;
            if constexpr (sizeof(TA) == 4) {
                float4 v0 = aok ? *(const float4*)((const float*)ap + i * 8 + 0)
                                : make_float4(0.f, 0.f, 0.f, 0.f);
                float4 v1 = aok ? *(const float4*)((const float*)ap + i * 8 + 4)
                                : make_float4(0.f, 0.f, 0.f, 0.f);
                h[0] = (_Float16)v0.x; h[1] = (_Float16)v0.y;
                h[2] = (_Float16)v0.z; h[3] = (_Float16)v0.w;
                h[4] = (_Float16)v1.x; h[5] = (_Float16)v1.y;
                h[6] = (_Float16)v1.z; h[7] = (_Float16)v1.w;
            } else {
                h = aok ? *(const half8*)((const _Float16*)ap + i * 8)
                        : half8{0, 0, 0, 0, 0, 0, 0, 0};
            }
            *(half8*)&Asl[srow * PK + skh + i * 8] = h;
        }
        // --- stage B transposed ([n][k]), 16 elems/thread ---
#pragma unroll
        for (int r = 0; r < 4; ++r) {
            int kk = bk + r * 16;
            float4 wv = *(const float4*)(B + (size_t)(k0 + kk) * N + col0 + bn);
            Bsl[(bn + 0) * PK + kk] = (_Float16)wv.x;
            Bsl[(bn + 1) * PK + kk] = (_Float16)wv.y;
            Bsl[(bn + 2) * PK + kk] = (_Float16)wv.z;
            Bsl[(bn + 3) * PK + kk] = (_Float16)wv.w;
        }
        __syncthreads();

#pragma unroll
        for (int kr = 0; kr < 2; ++kr) {
            half8 af[2], bf[4];
#pragma unroll
            for (int m = 0; m < 2; ++m)
                af[m] = *(half8*)&Asl[(wr + m * 16 + lr) * PK + kr * 32 + lg * 8];
#pragma unroll
            for (int n = 0; n < 4; ++n)
                bf[n] = *(half8*)&Bsl[(n * 16 + lr) * PK + kr * 32 + lg * 8];
#pragma unroll
            for (int m = 0; m < 2; ++m)
#pragma unroll
                for (int n = 0; n < 4; ++n)
                    acc[m][n] = __builtin_amdgcn_mfma_f32_16x16x32_f16(
                        af[m], bf[n], acc[m][n], 0, 0, 0);
        }
        __syncthreads();
    }

#pragma unroll
    for (int m = 0; m < 2; ++m) {
#pragma unroll
        for (int r = 0; r < 4; ++r) {
            int row = row0 + wr + m * 16 + lg * 4 + r;
            if (row >= M) continue;
#pragma unroll
            for (int n = 0; n < 4; ++n) {
                int col = col0 + n * 16 + lr;
                float v = acc[m][n][r];
                if (RELU) v = fmaxf(v + bias[col], 0.f);
                C[(size_t)row * N + col] = (_Float16)v;
            }
        }
    }
}

// ---------------------------------------------------------------------------
// Gather aggregation (fp16 H, fp32 accumulate, fp16 out).
// One wave per (node, 64-col segment).
//   O[i,col] = dinv[i]^2*H[i,col] + sum_e norm_e*H[src_e,col]   (+bias,relu)
// bias == nullptr -> raw aggregate.
// ---------------------------------------------------------------------------
__global__ __launch_bounds__(256) void k_gather(const int* __restrict__ row_ptr,
                                                const float2* __restrict__ csr,
                                                const _Float16* __restrict__ H,
                                                const float* __restrict__ dinv,
                                                const float* __restrict__ b,
                                                _Float16* __restrict__ O,
                                                int n, int fo, int shift) {
    int wave = blockIdx.x * 4 + (threadIdx.x >> 6);
    int lane = threadIdx.x & 63;
    int node = wave >> shift;
    if (node >= n) return;
    int col = ((wave & ((1 << shift) - 1)) << 6) + lane;

    float di = dinv[node];
    float acc = di * di * (float)H[(size_t)node * fo + col];

    int e = row_ptr[node];
    int e1 = row_ptr[node + 1];
    for (; e + 3 < e1; e += 4) {
        float2 c0 = csr[e + 0];
        float2 c1 = csr[e + 1];
        float2 c2 = csr[e + 2];
        float2 c3 = csr[e + 3];
        float h0 = (float)H[(size_t)__float_as_int(c0.x) * fo + col];
        float h1 = (float)H[(size_t)__float_as_int(c1.x) * fo + col];
        float h2 = (float)H[(size_t)__float_as_int(c2.x) * fo + col];
        float h3 = (float)H[(size_t)__float_as_int(c3.x) * fo + col];
        acc += c0.y * h0;
        acc += c1.y * h1;
        acc += c2.y * h2;
        acc += c3.y * h3;
    }
    for (; e < e1; ++e) {
        float2 c = csr[e];
        acc += c.y * (float)H[(size_t)__float_as_int(c.x) * fo + col];
    }

    if (b != nullptr) {
        acc += b[col];
        acc = fmaxf(acc, 0.f);
    }
    O[(size_t)node * fo + col] = (_Float16)acc;
}

// ---------------------------------------------------------------------------
// Fused layer-4 gather + bias + relu + final Linear(256,1). fp16 H, fp32 out.
// ---------------------------------------------------------------------------
__global__ __launch_bounds__(256) void k_gather_final(const int* __restrict__ row_ptr,
                                                      const float2* __restrict__ csr,
                                                      const _Float16* __restrict__ H,
                                                      const float* __restrict__ dinv,
                                                      const float* __restrict__ b4,
                                                      const float* __restrict__ Wf,
                                                      const float* __restrict__ bf,
                                                      float* __restrict__ out, int n) {
    __shared__ float red[4];
    int node = blockIdx.x;
    if (node >= n) return;
    int w = threadIdx.x >> 6;
    int lane = threadIdx.x & 63;
    int col = (w << 6) + lane;

    float di = dinv[node];
    float acc = di * di * (float)H[(size_t)node * 256 + col];

    int e = row_ptr[node];
    int e1 = row_ptr[node + 1];
    for (; e + 3 < e1; e += 4) {
        float2 c0 = csr[e + 0];
        float2 c1 = csr[e + 1];
        float2 c2 = csr[e + 2];
        float2 c3 = csr[e + 3];
        float h0 = (float)H[(size_t)__float_as_int(c0.x) * 256 + col];
        float h1 = (float)H[(size_t)__float_as_int(c1.x) * 256 + col];
        float h2 = (float)H[(size_t)__float_as_int(c2.x) * 256 + col];
        float h3 = (float)H[(size_t)__float_as_int(c3.x) * 256 + col];
        acc += c0.y * h0;
        acc += c1.y * h1;
        acc += c2.y * h2;
        acc += c3.y * h3;
    }
    for (; e < e1; ++e) {
        float2 c = csr[e];
        acc += c.y * (float)H[(size_t)__float_as_int(c.x) * 256 + col];
    }

    float v = fmaxf(acc + b4[col], 0.f) * Wf[col];
#pragma unroll
    for (int off = 32; off > 0; off >>= 1) v += __shfl_down(v, off);
    if (lane == 0) red[w] = v;
    __syncthreads();
    if (threadIdx.x == 0)
        out[node] = red[0] + red[1] + red[2] + red[3] + bf[0];
}

// ---------------------------------------------------------------------------

extern "C" void kernel_launch(void* const* d_in, const int* in_sizes, int n_in,
                              void* d_out, int out_size, void* d_ws, size_t ws_size,
                              hipStream_t stream) {
    const float* x    = (const float*)d_in[0];
    const int*   eidx = (const int*)d_in[1];
    const float* eatt = (const float*)d_in[2];
    const float* W1 = (const float*)d_in[3];
    const float* b1 = (const float*)d_in[4];
    const float* W2 = (const float*)d_in[5];
    const float* b2 = (const float*)d_in[6];
    const float* W3 = (const float*)d_in[7];
    const float* b3 = (const float*)d_in[8];
    const float* W4 = (const float*)d_in[9];
    const float* b4 = (const float*)d_in[10];
    const float* Wf = (const float*)d_in[11];
    const float* bf = (const float*)d_in[12];

    const int NN = in_sizes[0] / 128;   // 50000
    const int NE = in_sizes[2];         // 800000
    const int* src = eidx;              // edge_index[0]
    const int* dst = eidx + NE;         // edge_index[1]

    // workspace layout
    const int Na = (NN + 64) & ~63;
    float* ws      = (float*)d_ws;
    float* dinv    = ws;                        // N floats
    int*   row_ptr = (int*)(ws + Na);           // N+1 ints
    int*   cnt     = row_ptr + Na;              // N ints (count, then cursor)
    float2* csr    = (float2*)(cnt + Na);       // E float2 (src, norm)
    _Float16* bufA = (_Float16*)(csr + NE);     // N*256 halves
    _Float16* bufB = bufA + (size_t)NN * 256;   // N*256 halves

    // --- graph preprocessing ---
    k_init<<<(NN + 255) / 256, 256, 0, stream>>>(dinv, cnt, NN);
    k_count_deg<<<(NE + 255) / 256, 256, 0, stream>>>(dst, eatt, dinv, cnt, NE);
    k_dinv<<<(NN + 255) / 256, 256, 0, stream>>>(dinv, NN);
    k_scan<<<1, 1024, 0, stream>>>(cnt, row_ptr, cnt, NN);
    k_fill<<<(NE + 255) / 256, 256, 0, stream>>>(src, dst, eatt, dinv, row_ptr, cnt, csr, NE);

    int gw = (NN + 3) / 4;
    int gx = (NN + 127) / 128;

    // --- L1 (128->64), aggregate AFTER: H1 = x@W1; h1 = relu(gather(H1)+b1)
    gemm_mfma<false, float><<<dim3(gx, 1), 256, 0, stream>>>(x, W1, nullptr, bufB, NN, 128, 64);
    k_gather<<<gw, 256, 0, stream>>>(row_ptr, csr, bufB, dinv, b1, bufA, NN, 64, 0);

    // --- L2 (64->128), aggregate BEFORE: g2 = gather(h1); h2 = relu(g2@W2+b2)
    k_gather<<<gw, 256, 0, stream>>>(row_ptr, csr, bufA, dinv, nullptr, bufB, NN, 64, 0);
    gemm_mfma<true, _Float16><<<dim3(gx, 2), 256, 0, stream>>>(bufB, W2, b2, bufA, NN, 64, 128);

    // --- L3 (128->256), aggregate BEFORE: g3 = gather(h2); h3 = relu(g3@W3+b3)
    k_gather<<<(NN * 2 + 3) / 4, 256, 0, stream>>>(row_ptr, csr, bufA, dinv, nullptr, bufB, NN, 128, 1);
    gemm_mfma<true, _Float16><<<dim3(gx, 4), 256, 0, stream>>>(bufB, W3, b3, bufA, NN, 128, 256);

    // --- L4 (256->256) aggregate AFTER + fused final dot
    gemm_mfma<false, _Float16><<<dim3(gx, 4), 256, 0, stream>>>(bufA, W4, nullptr, bufB, NN, 256, 256);
    k_gather_final<<<NN, 256, 0, stream>>>(row_ptr, csr, bufB, dinv, b4, Wf, bf,
                                           (float*)d_out, NN);
}

// Round 6
// 446.695 us; speedup vs baseline: 17.1981x; 1.2265x over previous
//
#include <hip/hip_runtime.h>
#include <math.h>

// ---------------------------------------------------------------------------
// EdgeCorrGNN: 4x GCNConv(+relu) + Linear(256,1).
// R6: single-block scan (111us, 20% of runtime) -> 3-kernel parallel scan.
// fp16 intermediates + fp16-MFMA GEMMs (R5) retained.
// ---------------------------------------------------------------------------

typedef _Float16 half8 __attribute__((ext_vector_type(8)));
typedef float f32x4 __attribute__((ext_vector_type(4)));

#define SCAN_CHUNK 2048   // elements per scan block (256 thr x 8)

__global__ __launch_bounds__(256) void k_init(float* __restrict__ deg,
                                              int* __restrict__ cnt, int n) {
    int i = blockIdx.x * 256 + threadIdx.x;
    if (i < n) { deg[i] = 1.0f; cnt[i] = 0; }  // self-loop weight folded into deg
}

__global__ __launch_bounds__(256) void k_count_deg(const int* __restrict__ dst,
                                                   const float* __restrict__ w,
                                                   float* __restrict__ deg,
                                                   int* __restrict__ cnt, int e) {
    int i = blockIdx.x * 256 + threadIdx.x;
    if (i < e) {
        int d = dst[i];
        atomicAdd(&deg[d], w[i]);
        atomicAdd(&cnt[d], 1);
    }
}

__global__ __launch_bounds__(256) void k_dinv(float* __restrict__ deg, int n) {
    int i = blockIdx.x * 256 + threadIdx.x;
    if (i < n) {
        float d = deg[i];
        deg[i] = d > 0.0f ? rsqrtf(d) : 0.0f;  // in-place deg -> dinv
    }
}

// --- parallel exclusive scan, 3 kernels -----------------------------------
// part: per-block local exclusive scan (into row_ptr) + per-block total.
__global__ __launch_bounds__(256) void k_scan_part(const int* __restrict__ cnt,
                                                   int* __restrict__ row_ptr,
                                                   int* __restrict__ blocksum, int n) {
    __shared__ int sp[256];
    int tid = threadIdx.x;
    int base = blockIdx.x * SCAN_CHUNK + tid * 8;
    int4 v0 = make_int4(0, 0, 0, 0), v1 = make_int4(0, 0, 0, 0);
    if (base < n) {                      // n % 8 == 0 -> whole-thread guard
        v0 = *(const int4*)(cnt + base);
        v1 = *(const int4*)(cnt + base + 4);
    }
    int s = v0.x + v0.y + v0.z + v0.w + v1.x + v1.y + v1.z + v1.w;
    sp[tid] = s;
    __syncthreads();
    for (int d = 1; d < 256; d <<= 1) {
        int t = (tid >= d) ? sp[tid - d] : 0;
        __syncthreads();
        sp[tid] += t;
        __syncthreads();
    }
    int off = (tid == 0) ? 0 : sp[tid - 1];
    if (base < n) {
        int o[8] = {v0.x, v0.y, v0.z, v0.w, v1.x, v1.y, v1.z, v1.w};
        int run = off;
#pragma unroll
        for (int i = 0; i < 8; ++i) { int c = o[i]; o[i] = run; run += c; }
        *(int4*)(row_ptr + base)     = make_int4(o[0], o[1], o[2], o[3]);
        *(int4*)(row_ptr + base + 4) = make_int4(o[4], o[5], o[6], o[7]);
    }
    if (tid == 255) blocksum[blockIdx.x] = sp[255];
}

// mid: one wave exclusive-scans the (<=64) block sums.
__global__ __launch_bounds__(64) void k_scan_mid(const int* __restrict__ blocksum,
                                                 int* __restrict__ blockoff, int nb) {
    int lane = threadIdx.x;
    int c = (lane < nb) ? blocksum[lane] : 0;
    int v = c;
    for (int d = 1; d < 64; d <<= 1) {
        int t = __shfl_up(v, d);
        if (lane >= d) v += t;
    }
    if (lane < nb) blockoff[lane] = v - c;
}

// add: row_ptr[i] += blockoff[chunk]; cursor[i] = 0; row_ptr[n] = total.
__global__ __launch_bounds__(256) void k_scan_add(int* __restrict__ row_ptr,
                                                  const int* __restrict__ blockoff,
                                                  int* __restrict__ cursor,
                                                  int n, int total) {
    int tid = threadIdx.x;
    int base = blockIdx.x * SCAN_CHUNK + tid * 8;
    if (base < n) {
        int off = blockoff[blockIdx.x];
        int4 a = *(const int4*)(row_ptr + base);
        int4 b = *(const int4*)(row_ptr + base + 4);
        a.x += off; a.y += off; a.z += off; a.w += off;
        b.x += off; b.y += off; b.z += off; b.w += off;
        *(int4*)(row_ptr + base)     = a;
        *(int4*)(row_ptr + base + 4) = b;
        *(int4*)(cursor + base)      = make_int4(0, 0, 0, 0);
        *(int4*)(cursor + base + 4)  = make_int4(0, 0, 0, 0);
    }
    if (blockIdx.x == 0 && tid == 0) row_ptr[n] = total;
}

// csr[slot] = (src, norm) for each edge, grouped by dst.
__global__ __launch_bounds__(256) void k_fill(const int* __restrict__ src,
                                              const int* __restrict__ dst,
                                              const float* __restrict__ w,
                                              const float* __restrict__ dinv,
                                              const int* __restrict__ row_ptr,
                                              int* __restrict__ cursor,
                                              float2* __restrict__ csr, int e) {
    int i = blockIdx.x * 256 + threadIdx.x;
    if (i < e) {
        int d = dst[i], s = src[i];
        float nv = dinv[s] * w[i] * dinv[d];
        int slot = row_ptr[d] + atomicAdd(&cursor[d], 1);
        csr[slot] = make_float2(__int_as_float(s), nv);
    }
}

// ---------------------------------------------------------------------------
// fp16-MFMA GEMM: C[M,N] = A[M,K]@B[K,N] (+bias, relu). A fp32 or fp16;
// B/bias fp32; C fp16.  BM=128, BN=64, BK=64; 4 waves x (32rows x 64cols).
// ---------------------------------------------------------------------------
template <bool RELU, typename TA>
__global__ __launch_bounds__(256) void gemm_mfma(const TA* __restrict__ A,
                                                 const float* __restrict__ B,
                                                 const float* __restrict__ bias,
                                                 _Float16* __restrict__ C,
                                                 int M, int K, int N) {
    constexpr int PK = 72;
    __shared__ _Float16 Asl[128 * PK];
    __shared__ _Float16 Bsl[64 * PK];

    int tid = threadIdx.x;
    int w = tid >> 6, l = tid & 63;
    int row0 = blockIdx.x * 128, col0 = blockIdx.y * 64;
    int wr = w * 32;
    int lr = l & 15, lg = l >> 4;

    int srow = tid >> 1;            // A staging: 0..127
    int skh = (tid & 1) * 32;       // half-row of 32 elems
    int bk = tid >> 4;              // B staging: k 0..15 (+16r)
    int bn = (tid & 15) * 4;        // n group of 4

    f32x4 acc[2][4] = {};

    for (int k0 = 0; k0 < K; k0 += 64) {
        const TA* ap = A + (size_t)(row0 + srow) * K + k0 + skh;
        bool aok = (row0 + srow) < M;
#pragma unroll
        for (int i = 0; i < 4; ++i) {
            half8 h;
            if constexpr (sizeof(TA) == 4) {
                float4 v0 = aok ? *(const float4*)((const float*)ap + i * 8 + 0)
                                : make_float4(0.f, 0.f, 0.f, 0.f);
                float4 v1 = aok ? *(const float4*)((const float*)ap + i * 8 + 4)
                                : make_float4(0.f, 0.f, 0.f, 0.f);
                h[0] = (_Float16)v0.x; h[1] = (_Float16)v0.y;
                h[2] = (_Float16)v0.z; h[3] = (_Float16)v0.w;
                h[4] = (_Float16)v1.x; h[5] = (_Float16)v1.y;
                h[6] = (_Float16)v1.z; h[7] = (_Float16)v1.w;
            } else {
                h = aok ? *(const half8*)((const _Float16*)ap + i * 8)
                        : half8{0, 0, 0, 0, 0, 0, 0, 0};
            }
            *(half8*)&Asl[srow * PK + skh + i * 8] = h;
        }
#pragma unroll
        for (int r = 0; r < 4; ++r) {
            int kk = bk + r * 16;
            float4 wv = *(const float4*)(B + (size_t)(k0 + kk) * N + col0 + bn);
            Bsl[(bn + 0) * PK + kk] = (_Float16)wv.x;
            Bsl[(bn + 1) * PK + kk] = (_Float16)wv.y;
            Bsl[(bn + 2) * PK + kk] = (_Float16)wv.z;
            Bsl[(bn + 3) * PK + kk] = (_Float16)wv.w;
        }
        __syncthreads();

#pragma unroll
        for (int kr = 0; kr < 2; ++kr) {
            half8 af[2], bf[4];
#pragma unroll
            for (int m = 0; m < 2; ++m)
                af[m] = *(half8*)&Asl[(wr + m * 16 + lr) * PK + kr * 32 + lg * 8];
#pragma unroll
            for (int n = 0; n < 4; ++n)
                bf[n] = *(half8*)&Bsl[(n * 16 + lr) * PK + kr * 32 + lg * 8];
#pragma unroll
            for (int m = 0; m < 2; ++m)
#pragma unroll
                for (int n = 0; n < 4; ++n)
                    acc[m][n] = __builtin_amdgcn_mfma_f32_16x16x32_f16(
                        af[m], bf[n], acc[m][n], 0, 0, 0);
        }
        __syncthreads();
    }

#pragma unroll
    for (int m = 0; m < 2; ++m) {
#pragma unroll
        for (int r = 0; r < 4; ++r) {
            int row = row0 + wr + m * 16 + lg * 4 + r;
            if (row >= M) continue;
#pragma unroll
            for (int n = 0; n < 4; ++n) {
                int col = col0 + n * 16 + lr;
                float v = acc[m][n][r];
                if (RELU) v = fmaxf(v + bias[col], 0.f);
                C[(size_t)row * N + col] = (_Float16)v;
            }
        }
    }
}

// ---------------------------------------------------------------------------
// Gather aggregation (fp16 H, fp32 accumulate, fp16 out).
// ---------------------------------------------------------------------------
__global__ __launch_bounds__(256) void k_gather(const int* __restrict__ row_ptr,
                                                const float2* __restrict__ csr,
                                                const _Float16* __restrict__ H,
                                                const float* __restrict__ dinv,
                                                const float* __restrict__ b,
                                                _Float16* __restrict__ O,
                                                int n, int fo, int shift) {
    int wave = blockIdx.x * 4 + (threadIdx.x >> 6);
    int lane = threadIdx.x & 63;
    int node = wave >> shift;
    if (node >= n) return;
    int col = ((wave & ((1 << shift) - 1)) << 6) + lane;

    float di = dinv[node];
    float acc = di * di * (float)H[(size_t)node * fo + col];

    int e = row_ptr[node];
    int e1 = row_ptr[node + 1];
    for (; e + 3 < e1; e += 4) {
        float2 c0 = csr[e + 0];
        float2 c1 = csr[e + 1];
        float2 c2 = csr[e + 2];
        float2 c3 = csr[e + 3];
        float h0 = (float)H[(size_t)__float_as_int(c0.x) * fo + col];
        float h1 = (float)H[(size_t)__float_as_int(c1.x) * fo + col];
        float h2 = (float)H[(size_t)__float_as_int(c2.x) * fo + col];
        float h3 = (float)H[(size_t)__float_as_int(c3.x) * fo + col];
        acc += c0.y * h0;
        acc += c1.y * h1;
        acc += c2.y * h2;
        acc += c3.y * h3;
    }
    for (; e < e1; ++e) {
        float2 c = csr[e];
        acc += c.y * (float)H[(size_t)__float_as_int(c.x) * fo + col];
    }

    if (b != nullptr) {
        acc += b[col];
        acc = fmaxf(acc, 0.f);
    }
    O[(size_t)node * fo + col] = (_Float16)acc;
}

// ---------------------------------------------------------------------------
// Fused layer-4 gather + bias + relu + final Linear(256,1). fp16 H, fp32 out.
// ---------------------------------------------------------------------------
__global__ __launch_bounds__(256) void k_gather_final(const int* __restrict__ row_ptr,
                                                      const float2* __restrict__ csr,
                                                      const _Float16* __restrict__ H,
                                                      const float* __restrict__ dinv,
                                                      const float* __restrict__ b4,
                                                      const float* __restrict__ Wf,
                                                      const float* __restrict__ bf,
                                                      float* __restrict__ out, int n) {
    __shared__ float red[4];
    int node = blockIdx.x;
    if (node >= n) return;
    int w = threadIdx.x >> 6;
    int lane = threadIdx.x & 63;
    int col = (w << 6) + lane;

    float di = dinv[node];
    float acc = di * di * (float)H[(size_t)node * 256 + col];

    int e = row_ptr[node];
    int e1 = row_ptr[node + 1];
    for (; e + 3 < e1; e += 4) {
        float2 c0 = csr[e + 0];
        float2 c1 = csr[e + 1];
        float2 c2 = csr[e + 2];
        float2 c3 = csr[e + 3];
        float h0 = (float)H[(size_t)__float_as_int(c0.x) * 256 + col];
        float h1 = (float)H[(size_t)__float_as_int(c1.x) * 256 + col];
        float h2 = (float)H[(size_t)__float_as_int(c2.x) * 256 + col];
        float h3 = (float)H[(size_t)__float_as_int(c3.x) * 256 + col];
        acc += c0.y * h0;
        acc += c1.y * h1;
        acc += c2.y * h2;
        acc += c3.y * h3;
    }
    for (; e < e1; ++e) {
        float2 c = csr[e];
        acc += c.y * (float)H[(size_t)__float_as_int(c.x) * 256 + col];
    }

    float v = fmaxf(acc + b4[col], 0.f) * Wf[col];
#pragma unroll
    for (int off = 32; off > 0; off >>= 1) v += __shfl_down(v, off);
    if (lane == 0) red[w] = v;
    __syncthreads();
    if (threadIdx.x == 0)
        out[node] = red[0] + red[1] + red[2] + red[3] + bf[0];
}

// ---------------------------------------------------------------------------

extern "C" void kernel_launch(void* const* d_in, const int* in_sizes, int n_in,
                              void* d_out, int out_size, void* d_ws, size_t ws_size,
                              hipStream_t stream) {
    const float* x    = (const float*)d_in[0];
    const int*   eidx = (const int*)d_in[1];
    const float* eatt = (const float*)d_in[2];
    const float* W1 = (const float*)d_in[3];
    const float* b1 = (const float*)d_in[4];
    const float* W2 = (const float*)d_in[5];
    const float* b2 = (const float*)d_in[6];
    const float* W3 = (const float*)d_in[7];
    const float* b3 = (const float*)d_in[8];
    const float* W4 = (const float*)d_in[9];
    const float* b4 = (const float*)d_in[10];
    const float* Wf = (const float*)d_in[11];
    const float* bf = (const float*)d_in[12];

    const int NN = in_sizes[0] / 128;   // 50000
    const int NE = in_sizes[2];         // 800000
    const int* src = eidx;              // edge_index[0]
    const int* dst = eidx + NE;         // edge_index[1]

    // workspace layout
    const int Na = (NN + 64) & ~63;
    float* ws      = (float*)d_ws;
    float* dinv    = ws;                        // N floats
    int*   row_ptr = (int*)(ws + Na);           // N+1 ints
    int*   cnt     = row_ptr + Na;              // N ints (count, then cursor)
    int*   bsum    = cnt + Na;                  // 64 ints
    int*   boff    = bsum + 64;                 // 64 ints
    float2* csr    = (float2*)(boff + 64);      // E float2 (src, norm)
    _Float16* bufA = (_Float16*)(csr + NE);     // N*256 halves
    _Float16* bufB = bufA + (size_t)NN * 256;   // N*256 halves

    const int nscan = (NN + SCAN_CHUNK - 1) / SCAN_CHUNK;   // 25

    // --- graph preprocessing ---
    k_init<<<(NN + 255) / 256, 256, 0, stream>>>(dinv, cnt, NN);
    k_count_deg<<<(NE + 255) / 256, 256, 0, stream>>>(dst, eatt, dinv, cnt, NE);
    k_dinv<<<(NN + 255) / 256, 256, 0, stream>>>(dinv, NN);
    k_scan_part<<<nscan, 256, 0, stream>>>(cnt, row_ptr, bsum, NN);
    k_scan_mid<<<1, 64, 0, stream>>>(bsum, boff, nscan);
    k_scan_add<<<nscan, 256, 0, stream>>>(row_ptr, boff, cnt, NN, NE);
    k_fill<<<(NE + 255) / 256, 256, 0, stream>>>(src, dst, eatt, dinv, row_ptr, cnt, csr, NE);

    int gw = (NN + 3) / 4;
    int gx = (NN + 127) / 128;

    // --- L1 (128->64), aggregate AFTER: H1 = x@W1; h1 = relu(gather(H1)+b1)
    gemm_mfma<false, float><<<dim3(gx, 1), 256, 0, stream>>>(x, W1, nullptr, bufB, NN, 128, 64);
    k_gather<<<gw, 256, 0, stream>>>(row_ptr, csr, bufB, dinv, b1, bufA, NN, 64, 0);

    // --- L2 (64->128), aggregate BEFORE: g2 = gather(h1); h2 = relu(g2@W2+b2)
    k_gather<<<gw, 256, 0, stream>>>(row_ptr, csr, bufA, dinv, nullptr, bufB, NN, 64, 0);
    gemm_mfma<true, _Float16><<<dim3(gx, 2), 256, 0, stream>>>(bufB, W2, b2, bufA, NN, 64, 128);

    // --- L3 (128->256), aggregate BEFORE: g3 = gather(h2); h3 = relu(g3@W3+b3)
    k_gather<<<(NN * 2 + 3) / 4, 256, 0, stream>>>(row_ptr, csr, bufA, dinv, nullptr, bufB, NN, 128, 1);
    gemm_mfma<true, _Float16><<<dim3(gx, 4), 256, 0, stream>>>(bufB, W3, b3, bufA, NN, 128, 256);

    // --- L4 (256->256) aggregate AFTER + fused final dot
    gemm_mfma<false, _Float16><<<dim3(gx, 4), 256, 0, stream>>>(bufA, W4, nullptr, bufB, NN, 256, 256);
    k_gather_final<<<NN, 256, 0, stream>>>(row_ptr, csr, bufB, dinv, b4, Wf, bf,
                                           (float*)d_out, NN);
}

// Round 7
// 362.999 us; speedup vs baseline: 21.1635x; 1.2306x over previous
//
#include <hip/hip_runtime.h>
#include <math.h>

// ---------------------------------------------------------------------------
// EdgeCorrGNN: 4x GCNConv(+relu) + Linear(256,1).
// R7: gathers -> one wave per node, half4 per lane, lane-groups process
// multiple edges concurrently (4x outstanding bytes vs R6). fp16 + MFMA kept.
// ---------------------------------------------------------------------------

typedef _Float16 half8 __attribute__((ext_vector_type(8)));
typedef _Float16 half4_t __attribute__((ext_vector_type(4)));
typedef float f32x4 __attribute__((ext_vector_type(4)));

#define SCAN_CHUNK 2048   // elements per scan block (256 thr x 8)

__global__ __launch_bounds__(256) void k_init(float* __restrict__ deg,
                                              int* __restrict__ cnt, int n) {
    int i = blockIdx.x * 256 + threadIdx.x;
    if (i < n) { deg[i] = 1.0f; cnt[i] = 0; }  // self-loop weight folded into deg
}

__global__ __launch_bounds__(256) void k_count_deg(const int* __restrict__ dst,
                                                   const float* __restrict__ w,
                                                   float* __restrict__ deg,
                                                   int* __restrict__ cnt, int e) {
    int i = blockIdx.x * 256 + threadIdx.x;
    if (i < e) {
        int d = dst[i];
        atomicAdd(&deg[d], w[i]);
        atomicAdd(&cnt[d], 1);
    }
}

__global__ __launch_bounds__(256) void k_dinv(float* __restrict__ deg, int n) {
    int i = blockIdx.x * 256 + threadIdx.x;
    if (i < n) {
        float d = deg[i];
        deg[i] = d > 0.0f ? rsqrtf(d) : 0.0f;  // in-place deg -> dinv
    }
}

// --- parallel exclusive scan, 3 kernels -----------------------------------
__global__ __launch_bounds__(256) void k_scan_part(const int* __restrict__ cnt,
                                                   int* __restrict__ row_ptr,
                                                   int* __restrict__ blocksum, int n) {
    __shared__ int sp[256];
    int tid = threadIdx.x;
    int base = blockIdx.x * SCAN_CHUNK + tid * 8;
    int4 v0 = make_int4(0, 0, 0, 0), v1 = make_int4(0, 0, 0, 0);
    if (base < n) {
        v0 = *(const int4*)(cnt + base);
        v1 = *(const int4*)(cnt + base + 4);
    }
    int s = v0.x + v0.y + v0.z + v0.w + v1.x + v1.y + v1.z + v1.w;
    sp[tid] = s;
    __syncthreads();
    for (int d = 1; d < 256; d <<= 1) {
        int t = (tid >= d) ? sp[tid - d] : 0;
        __syncthreads();
        sp[tid] += t;
        __syncthreads();
    }
    int off = (tid == 0) ? 0 : sp[tid - 1];
    if (base < n) {
        int o[8] = {v0.x, v0.y, v0.z, v0.w, v1.x, v1.y, v1.z, v1.w};
        int run = off;
#pragma unroll
        for (int i = 0; i < 8; ++i) { int c = o[i]; o[i] = run; run += c; }
        *(int4*)(row_ptr + base)     = make_int4(o[0], o[1], o[2], o[3]);
        *(int4*)(row_ptr + base + 4) = make_int4(o[4], o[5], o[6], o[7]);
    }
    if (tid == 255) blocksum[blockIdx.x] = sp[255];
}

__global__ __launch_bounds__(64) void k_scan_mid(const int* __restrict__ blocksum,
                                                 int* __restrict__ blockoff, int nb) {
    int lane = threadIdx.x;
    int c = (lane < nb) ? blocksum[lane] : 0;
    int v = c;
    for (int d = 1; d < 64; d <<= 1) {
        int t = __shfl_up(v, d);
        if (lane >= d) v += t;
    }
    if (lane < nb) blockoff[lane] = v - c;
}

__global__ __launch_bounds__(256) void k_scan_add(int* __restrict__ row_ptr,
                                                  const int* __restrict__ blockoff,
                                                  int* __restrict__ cursor,
                                                  int n, int total) {
    int tid = threadIdx.x;
    int base = blockIdx.x * SCAN_CHUNK + tid * 8;
    if (base < n) {
        int off = blockoff[blockIdx.x];
        int4 a = *(const int4*)(row_ptr + base);
        int4 b = *(const int4*)(row_ptr + base + 4);
        a.x += off; a.y += off; a.z += off; a.w += off;
        b.x += off; b.y += off; b.z += off; b.w += off;
        *(int4*)(row_ptr + base)     = a;
        *(int4*)(row_ptr + base + 4) = b;
        *(int4*)(cursor + base)      = make_int4(0, 0, 0, 0);
        *(int4*)(cursor + base + 4)  = make_int4(0, 0, 0, 0);
    }
    if (blockIdx.x == 0 && tid == 0) row_ptr[n] = total;
}

// csr[slot] = (src, norm) for each edge, grouped by dst.
__global__ __launch_bounds__(256) void k_fill(const int* __restrict__ src,
                                              const int* __restrict__ dst,
                                              const float* __restrict__ w,
                                              const float* __restrict__ dinv,
                                              const int* __restrict__ row_ptr,
                                              int* __restrict__ cursor,
                                              float2* __restrict__ csr, int e) {
    int i = blockIdx.x * 256 + threadIdx.x;
    if (i < e) {
        int d = dst[i], s = src[i];
        float nv = dinv[s] * w[i] * dinv[d];
        int slot = row_ptr[d] + atomicAdd(&cursor[d], 1);
        csr[slot] = make_float2(__int_as_float(s), nv);
    }
}

// ---------------------------------------------------------------------------
// fp16-MFMA GEMM: C[M,N] = A[M,K]@B[K,N] (+bias, relu). A fp32 or fp16;
// B/bias fp32; C fp16.  BM=128, BN=64, BK=64; 4 waves x (32rows x 64cols).
// ---------------------------------------------------------------------------
template <bool RELU, typename TA>
__global__ __launch_bounds__(256) void gemm_mfma(const TA* __restrict__ A,
                                                 const float* __restrict__ B,
                                                 const float* __restrict__ bias,
                                                 _Float16* __restrict__ C,
                                                 int M, int K, int N) {
    constexpr int PK = 72;
    __shared__ _Float16 Asl[128 * PK];
    __shared__ _Float16 Bsl[64 * PK];

    int tid = threadIdx.x;
    int w = tid >> 6, l = tid & 63;
    int row0 = blockIdx.x * 128, col0 = blockIdx.y * 64;
    int wr = w * 32;
    int lr = l & 15, lg = l >> 4;

    int srow = tid >> 1;
    int skh = (tid & 1) * 32;
    int bk = tid >> 4;
    int bn = (tid & 15) * 4;

    f32x4 acc[2][4] = {};

    for (int k0 = 0; k0 < K; k0 += 64) {
        const TA* ap = A + (size_t)(row0 + srow) * K + k0 + skh;
        bool aok = (row0 + srow) < M;
#pragma unroll
        for (int i = 0; i < 4; ++i) {
            half8 h;
            if constexpr (sizeof(TA) == 4) {
                float4 v0 = aok ? *(const float4*)((const float*)ap + i * 8 + 0)
                                : make_float4(0.f, 0.f, 0.f, 0.f);
                float4 v1 = aok ? *(const float4*)((const float*)ap + i * 8 + 4)
                                : make_float4(0.f, 0.f, 0.f, 0.f);
                h[0] = (_Float16)v0.x; h[1] = (_Float16)v0.y;
                h[2] = (_Float16)v0.z; h[3] = (_Float16)v0.w;
                h[4] = (_Float16)v1.x; h[5] = (_Float16)v1.y;
                h[6] = (_Float16)v1.z; h[7] = (_Float16)v1.w;
            } else {
                h = aok ? *(const half8*)((const _Float16*)ap + i * 8)
                        : half8{0, 0, 0, 0, 0, 0, 0, 0};
            }
            *(half8*)&Asl[srow * PK + skh + i * 8] = h;
        }
#pragma unroll
        for (int r = 0; r < 4; ++r) {
            int kk = bk + r * 16;
            float4 wv = *(const float4*)(B + (size_t)(k0 + kk) * N + col0 + bn);
            Bsl[(bn + 0) * PK + kk] = (_Float16)wv.x;
            Bsl[(bn + 1) * PK + kk] = (_Float16)wv.y;
            Bsl[(bn + 2) * PK + kk] = (_Float16)wv.z;
            Bsl[(bn + 3) * PK + kk] = (_Float16)wv.w;
        }
        __syncthreads();

#pragma unroll
        for (int kr = 0; kr < 2; ++kr) {
            half8 af[2], bf[4];
#pragma unroll
            for (int m = 0; m < 2; ++m)
                af[m] = *(half8*)&Asl[(wr + m * 16 + lr) * PK + kr * 32 + lg * 8];
#pragma unroll
            for (int n = 0; n < 4; ++n)
                bf[n] = *(half8*)&Bsl[(n * 16 + lr) * PK + kr * 32 + lg * 8];
#pragma unroll
            for (int m = 0; m < 2; ++m)
#pragma unroll
                for (int n = 0; n < 4; ++n)
                    acc[m][n] = __builtin_amdgcn_mfma_f32_16x16x32_f16(
                        af[m], bf[n], acc[m][n], 0, 0, 0);
        }
        __syncthreads();
    }

#pragma unroll
    for (int m = 0; m < 2; ++m) {
#pragma unroll
        for (int r = 0; r < 4; ++r) {
            int row = row0 + wr + m * 16 + lg * 4 + r;
            if (row >= M) continue;
#pragma unroll
            for (int n = 0; n < 4; ++n) {
                int col = col0 + n * 16 + lr;
                float v = acc[m][n][r];
                if (RELU) v = fmaxf(v + bias[col], 0.f);
                C[(size_t)row * N + col] = (_Float16)v;
            }
        }
    }
}

// ---------------------------------------------------------------------------
// Gather v2: ONE WAVE PER NODE. Each lane owns 4 cols (half4, 8B load);
// lane-group g = lane/LPE processes edge e+g concurrently (LPE = FO/4 lanes
// per edge, GRP = 64/LPE edges in parallel). 4-step unroll -> 4 half4 loads
// in flight per lane (2 KB/wave outstanding). Tail: clamp index, zero weight.
// Cross-group reduce via shfl at stride LPE. Lanes < LPE finalize.
// ---------------------------------------------------------------------------
template <int FO, bool BIASRELU>
__global__ __launch_bounds__(256) void k_gather2(const int* __restrict__ row_ptr,
                                                 const float2* __restrict__ csr,
                                                 const _Float16* __restrict__ H,
                                                 const float* __restrict__ dinv,
                                                 const float* __restrict__ b,
                                                 _Float16* __restrict__ O, int n) {
    constexpr int LPE = FO / 4;     // lanes per edge
    constexpr int GRP = 64 / LPE;   // edges processed in parallel
    int node = blockIdx.x * 4 + (threadIdx.x >> 6);
    int lane = threadIdx.x & 63;
    if (node >= n) return;
    int grp = lane / LPE;
    int cols = (lane % LPE) * 4;

    float ax = 0.f, ay = 0.f, az = 0.f, aw = 0.f;
    int e0 = row_ptr[node], e1 = row_ptr[node + 1];

    for (int e = e0; e < e1; e += 4 * GRP) {
        float nv[4]; half4_t hv[4];
#pragma unroll
        for (int u = 0; u < 4; ++u) {
            int er = e + u * GRP + grp;
            int eg = min(er, e1 - 1);
            float2 c = csr[eg];
            hv[u] = *(const half4_t*)(H + (size_t)__float_as_int(c.x) * FO + cols);
            nv[u] = (er < e1) ? c.y : 0.f;
        }
#pragma unroll
        for (int u = 0; u < 4; ++u) {
            ax += nv[u] * (float)hv[u][0];
            ay += nv[u] * (float)hv[u][1];
            az += nv[u] * (float)hv[u][2];
            aw += nv[u] * (float)hv[u][3];
        }
    }

#pragma unroll
    for (int off = LPE; off < 64; off <<= 1) {
        ax += __shfl_down(ax, off);
        ay += __shfl_down(ay, off);
        az += __shfl_down(az, off);
        aw += __shfl_down(aw, off);
    }

    if (lane < LPE) {
        float di = dinv[node];
        float s = di * di;
        half4_t hs = *(const half4_t*)(H + (size_t)node * FO + cols);
        ax += s * (float)hs[0];
        ay += s * (float)hs[1];
        az += s * (float)hs[2];
        aw += s * (float)hs[3];
        if (BIASRELU) {
            float4 bv = *(const float4*)(b + cols);
            ax = fmaxf(ax + bv.x, 0.f);
            ay = fmaxf(ay + bv.y, 0.f);
            az = fmaxf(az + bv.z, 0.f);
            aw = fmaxf(aw + bv.w, 0.f);
        }
        half4_t o;
        o[0] = (_Float16)ax; o[1] = (_Float16)ay;
        o[2] = (_Float16)az; o[3] = (_Float16)aw;
        *(half4_t*)(O + (size_t)node * FO + cols) = o;
    }
}

// ---------------------------------------------------------------------------
// Fused layer-4 gather + bias + relu + final Linear(256,1).
// One wave per node (FO=256: 64 lanes x half4). Pure shfl reduction.
// ---------------------------------------------------------------------------
__global__ __launch_bounds__(256) void k_gather_final2(const int* __restrict__ row_ptr,
                                                       const float2* __restrict__ csr,
                                                       const _Float16* __restrict__ H,
                                                       const float* __restrict__ dinv,
                                                       const float* __restrict__ b4,
                                                       const float* __restrict__ Wf,
                                                       const float* __restrict__ bf,
                                                       float* __restrict__ out, int n) {
    int node = blockIdx.x * 4 + (threadIdx.x >> 6);
    int lane = threadIdx.x & 63;
    if (node >= n) return;
    int cols = lane * 4;

    float ax = 0.f, ay = 0.f, az = 0.f, aw = 0.f;
    int e0 = row_ptr[node], e1 = row_ptr[node + 1];

    for (int e = e0; e < e1; e += 4) {
        float nv[4]; half4_t hv[4];
#pragma unroll
        for (int u = 0; u < 4; ++u) {
            int er = e + u;
            int eg = min(er, e1 - 1);
            float2 c = csr[eg];
            hv[u] = *(const half4_t*)(H + (size_t)__float_as_int(c.x) * 256 + cols);
            nv[u] = (er < e1) ? c.y : 0.f;
        }
#pragma unroll
        for (int u = 0; u < 4; ++u) {
            ax += nv[u] * (float)hv[u][0];
            ay += nv[u] * (float)hv[u][1];
            az += nv[u] * (float)hv[u][2];
            aw += nv[u] * (float)hv[u][3];
        }
    }

    float di = dinv[node];
    float s = di * di;
    half4_t hs = *(const half4_t*)(H + (size_t)node * 256 + cols);
    float4 bv = *(const float4*)(b4 + cols);
    float4 wv = *(const float4*)(Wf + cols);
    float v = fmaxf(ax + s * (float)hs[0] + bv.x, 0.f) * wv.x
            + fmaxf(ay + s * (float)hs[1] + bv.y, 0.f) * wv.y
            + fmaxf(az + s * (float)hs[2] + bv.z, 0.f) * wv.z
            + fmaxf(aw + s * (float)hs[3] + bv.w, 0.f) * wv.w;
#pragma unroll
    for (int off = 32; off > 0; off >>= 1) v += __shfl_down(v, off);
    if (lane == 0) out[node] = v + bf[0];
}

// ---------------------------------------------------------------------------

extern "C" void kernel_launch(void* const* d_in, const int* in_sizes, int n_in,
                              void* d_out, int out_size, void* d_ws, size_t ws_size,
                              hipStream_t stream) {
    const float* x    = (const float*)d_in[0];
    const int*   eidx = (const int*)d_in[1];
    const float* eatt = (const float*)d_in[2];
    const float* W1 = (const float*)d_in[3];
    const float* b1 = (const float*)d_in[4];
    const float* W2 = (const float*)d_in[5];
    const float* b2 = (const float*)d_in[6];
    const float* W3 = (const float*)d_in[7];
    const float* b3 = (const float*)d_in[8];
    const float* W4 = (const float*)d_in[9];
    const float* b4 = (const float*)d_in[10];
    const float* Wf = (const float*)d_in[11];
    const float* bf = (const float*)d_in[12];

    const int NN = in_sizes[0] / 128;   // 50000
    const int NE = in_sizes[2];         // 800000
    const int* src = eidx;              // edge_index[0]
    const int* dst = eidx + NE;         // edge_index[1]

    // workspace layout
    const int Na = (NN + 64) & ~63;
    float* ws      = (float*)d_ws;
    float* dinv    = ws;                        // N floats
    int*   row_ptr = (int*)(ws + Na);           // N+1 ints
    int*   cnt     = row_ptr + Na;              // N ints (count, then cursor)
    int*   bsum    = cnt + Na;                  // 64 ints
    int*   boff    = bsum + 64;                 // 64 ints
    float2* csr    = (float2*)(boff + 64);      // E float2 (src, norm)
    _Float16* bufA = (_Float16*)(csr + NE);     // N*256 halves
    _Float16* bufB = bufA + (size_t)NN * 256;   // N*256 halves

    const int nscan = (NN + SCAN_CHUNK - 1) / SCAN_CHUNK;   // 25

    // --- graph preprocessing ---
    k_init<<<(NN + 255) / 256, 256, 0, stream>>>(dinv, cnt, NN);
    k_count_deg<<<(NE + 255) / 256, 256, 0, stream>>>(dst, eatt, dinv, cnt, NE);
    k_dinv<<<(NN + 255) / 256, 256, 0, stream>>>(dinv, NN);
    k_scan_part<<<nscan, 256, 0, stream>>>(cnt, row_ptr, bsum, NN);
    k_scan_mid<<<1, 64, 0, stream>>>(bsum, boff, nscan);
    k_scan_add<<<nscan, 256, 0, stream>>>(row_ptr, boff, cnt, NN, NE);
    k_fill<<<(NE + 255) / 256, 256, 0, stream>>>(src, dst, eatt, dinv, row_ptr, cnt, csr, NE);

    int gw = (NN + 3) / 4;   // one wave per node, 4 waves per block
    int gx = (NN + 127) / 128;

    // --- L1 (128->64), aggregate AFTER: H1 = x@W1; h1 = relu(gather(H1)+b1)
    gemm_mfma<false, float><<<dim3(gx, 1), 256, 0, stream>>>(x, W1, nullptr, bufB, NN, 128, 64);
    k_gather2<64, true><<<gw, 256, 0, stream>>>(row_ptr, csr, bufB, dinv, b1, bufA, NN);

    // --- L2 (64->128), aggregate BEFORE: g2 = gather(h1); h2 = relu(g2@W2+b2)
    k_gather2<64, false><<<gw, 256, 0, stream>>>(row_ptr, csr, bufA, dinv, nullptr, bufB, NN);
    gemm_mfma<true, _Float16><<<dim3(gx, 2), 256, 0, stream>>>(bufB, W2, b2, bufA, NN, 64, 128);

    // --- L3 (128->256), aggregate BEFORE: g3 = gather(h2); h3 = relu(g3@W3+b3)
    k_gather2<128, false><<<gw, 256, 0, stream>>>(row_ptr, csr, bufA, dinv, nullptr, bufB, NN);
    gemm_mfma<true, _Float16><<<dim3(gx, 4), 256, 0, stream>>>(bufB, W3, b3, bufA, NN, 128, 256);

    // --- L4 (256->256) aggregate AFTER + fused final dot
    gemm_mfma<false, _Float16><<<dim3(gx, 4), 256, 0, stream>>>(bufA, W4, nullptr, bufB, NN, 256, 256);
    k_gather_final2<<<gw, 256, 0, stream>>>(row_ptr, csr, bufB, dinv, b4, Wf, bf,
                                            (float*)d_out, NN);
}

// Round 8
// 299.280 us; speedup vs baseline: 25.6693x; 1.2129x over previous
//
#include <hip/hip_runtime.h>
#include <math.h>

// ---------------------------------------------------------------------------
// EdgeCorrGNN: 4x GCNConv(+relu) + Linear(256,1).
// R8: one u64 atomic per edge packs (count<<42 | fixed-point-deg); the atomic
// return value doubles as the CSR slot -> k_fill has zero atomics.
// ---------------------------------------------------------------------------

typedef _Float16 half8 __attribute__((ext_vector_type(8)));
typedef _Float16 half4_t __attribute__((ext_vector_type(4)));
typedef float f32x4 __attribute__((ext_vector_type(4)));

#define SCAN_CHUNK 2048           // elements per scan block (256 thr x 8)
#define DEG_SCALE 67108864.0f     // 2^26 fixed-point scale for weighted degree
#define DEG_MASK ((1ULL << 42) - 1)

__global__ __launch_bounds__(256) void k_init(unsigned long long* __restrict__ packed,
                                              int n) {
    int i = blockIdx.x * 256 + threadIdx.x;
    if (i < n) packed[i] = (1ULL << 26);   // deg = 1.0 (self-loop), cnt = 0
}

// one u64 atomic per edge; returned old count = slot within the dst row.
__global__ __launch_bounds__(256) void k_count_slot(const int* __restrict__ dst,
                                                    const float* __restrict__ w,
                                                    unsigned long long* __restrict__ packed,
                                                    int* __restrict__ slot, int e) {
    int i = blockIdx.x * 256 + threadIdx.x;
    if (i < e) {
        unsigned long long wf = (unsigned long long)(w[i] * DEG_SCALE + 0.5f);
        unsigned long long old = atomicAdd(&packed[dst[i]], (1ULL << 42) | wf);
        slot[i] = (int)(old >> 42);
    }
}

// unpack: dinv = rsqrt(deg), cnt for the scan.
__global__ __launch_bounds__(256) void k_dinv(const unsigned long long* __restrict__ packed,
                                              float* __restrict__ dinv,
                                              int* __restrict__ cnt, int n) {
    int i = blockIdx.x * 256 + threadIdx.x;
    if (i < n) {
        unsigned long long p = packed[i];
        float d = (float)((double)(p & DEG_MASK) * (1.0 / 67108864.0));
        dinv[i] = d > 0.0f ? rsqrtf(d) : 0.0f;
        cnt[i] = (int)(p >> 42);
    }
}

// --- parallel exclusive scan, 3 kernels -----------------------------------
__global__ __launch_bounds__(256) void k_scan_part(const int* __restrict__ cnt,
                                                   int* __restrict__ row_ptr,
                                                   int* __restrict__ blocksum, int n) {
    __shared__ int sp[256];
    int tid = threadIdx.x;
    int base = blockIdx.x * SCAN_CHUNK + tid * 8;
    int4 v0 = make_int4(0, 0, 0, 0), v1 = make_int4(0, 0, 0, 0);
    if (base < n) {
        v0 = *(const int4*)(cnt + base);
        v1 = *(const int4*)(cnt + base + 4);
    }
    int s = v0.x + v0.y + v0.z + v0.w + v1.x + v1.y + v1.z + v1.w;
    sp[tid] = s;
    __syncthreads();
    for (int d = 1; d < 256; d <<= 1) {
        int t = (tid >= d) ? sp[tid - d] : 0;
        __syncthreads();
        sp[tid] += t;
        __syncthreads();
    }
    int off = (tid == 0) ? 0 : sp[tid - 1];
    if (base < n) {
        int o[8] = {v0.x, v0.y, v0.z, v0.w, v1.x, v1.y, v1.z, v1.w};
        int run = off;
#pragma unroll
        for (int i = 0; i < 8; ++i) { int c = o[i]; o[i] = run; run += c; }
        *(int4*)(row_ptr + base)     = make_int4(o[0], o[1], o[2], o[3]);
        *(int4*)(row_ptr + base + 4) = make_int4(o[4], o[5], o[6], o[7]);
    }
    if (tid == 255) blocksum[blockIdx.x] = sp[255];
}

__global__ __launch_bounds__(64) void k_scan_mid(const int* __restrict__ blocksum,
                                                 int* __restrict__ blockoff, int nb) {
    int lane = threadIdx.x;
    int c = (lane < nb) ? blocksum[lane] : 0;
    int v = c;
    for (int d = 1; d < 64; d <<= 1) {
        int t = __shfl_up(v, d);
        if (lane >= d) v += t;
    }
    if (lane < nb) blockoff[lane] = v - c;
}

__global__ __launch_bounds__(256) void k_scan_add(int* __restrict__ row_ptr,
                                                  const int* __restrict__ blockoff,
                                                  int n, int total) {
    int tid = threadIdx.x;
    int base = blockIdx.x * SCAN_CHUNK + tid * 8;
    if (base < n) {
        int off = blockoff[blockIdx.x];
        int4 a = *(const int4*)(row_ptr + base);
        int4 b = *(const int4*)(row_ptr + base + 4);
        a.x += off; a.y += off; a.z += off; a.w += off;
        b.x += off; b.y += off; b.z += off; b.w += off;
        *(int4*)(row_ptr + base)     = a;
        *(int4*)(row_ptr + base + 4) = b;
    }
    if (blockIdx.x == 0 && tid == 0) row_ptr[n] = total;
}

// csr[row_ptr[dst] + slot] = (src, norm) -- pure scatter, no atomics.
__global__ __launch_bounds__(256) void k_fill(const int* __restrict__ src,
                                              const int* __restrict__ dst,
                                              const float* __restrict__ w,
                                              const float* __restrict__ dinv,
                                              const int* __restrict__ row_ptr,
                                              const int* __restrict__ slot,
                                              float2* __restrict__ csr, int e) {
    int i = blockIdx.x * 256 + threadIdx.x;
    if (i < e) {
        int d = dst[i], s = src[i];
        float nv = dinv[s] * w[i] * dinv[d];
        csr[row_ptr[d] + slot[i]] = make_float2(__int_as_float(s), nv);
    }
}

// ---------------------------------------------------------------------------
// fp16-MFMA GEMM: C[M,N] = A[M,K]@B[K,N] (+bias, relu). A fp32 or fp16;
// B/bias fp32; C fp16.  BM=128, BN=64, BK=64; 4 waves x (32rows x 64cols).
// ---------------------------------------------------------------------------
template <bool RELU, typename TA>
__global__ __launch_bounds__(256) void gemm_mfma(const TA* __restrict__ A,
                                                 const float* __restrict__ B,
                                                 const float* __restrict__ bias,
                                                 _Float16* __restrict__ C,
                                                 int M, int K, int N) {
    constexpr int PK = 72;
    __shared__ _Float16 Asl[128 * PK];
    __shared__ _Float16 Bsl[64 * PK];

    int tid = threadIdx.x;
    int w = tid >> 6, l = tid & 63;
    int row0 = blockIdx.x * 128, col0 = blockIdx.y * 64;
    int wr = w * 32;
    int lr = l & 15, lg = l >> 4;

    int srow = tid >> 1;
    int skh = (tid & 1) * 32;
    int bk = tid >> 4;
    int bn = (tid & 15) * 4;

    f32x4 acc[2][4] = {};

    for (int k0 = 0; k0 < K; k0 += 64) {
        const TA* ap = A + (size_t)(row0 + srow) * K + k0 + skh;
        bool aok = (row0 + srow) < M;
#pragma unroll
        for (int i = 0; i < 4; ++i) {
            half8 h;
            if constexpr (sizeof(TA) == 4) {
                float4 v0 = aok ? *(const float4*)((const float*)ap + i * 8 + 0)
                                : make_float4(0.f, 0.f, 0.f, 0.f);
                float4 v1 = aok ? *(const float4*)((const float*)ap + i * 8 + 4)
                                : make_float4(0.f, 0.f, 0.f, 0.f);
                h[0] = (_Float16)v0.x; h[1] = (_Float16)v0.y;
                h[2] = (_Float16)v0.z; h[3] = (_Float16)v0.w;
                h[4] = (_Float16)v1.x; h[5] = (_Float16)v1.y;
                h[6] = (_Float16)v1.z; h[7] = (_Float16)v1.w;
            } else {
                h = aok ? *(const half8*)((const _Float16*)ap + i * 8)
                        : half8{0, 0, 0, 0, 0, 0, 0, 0};
            }
            *(half8*)&Asl[srow * PK + skh + i * 8] = h;
        }
#pragma unroll
        for (int r = 0; r < 4; ++r) {
            int kk = bk + r * 16;
            float4 wv = *(const float4*)(B + (size_t)(k0 + kk) * N + col0 + bn);
            Bsl[(bn + 0) * PK + kk] = (_Float16)wv.x;
            Bsl[(bn + 1) * PK + kk] = (_Float16)wv.y;
            Bsl[(bn + 2) * PK + kk] = (_Float16)wv.z;
            Bsl[(bn + 3) * PK + kk] = (_Float16)wv.w;
        }
        __syncthreads();

#pragma unroll
        for (int kr = 0; kr < 2; ++kr) {
            half8 af[2], bf[4];
#pragma unroll
            for (int m = 0; m < 2; ++m)
                af[m] = *(half8*)&Asl[(wr + m * 16 + lr) * PK + kr * 32 + lg * 8];
#pragma unroll
            for (int n = 0; n < 4; ++n)
                bf[n] = *(half8*)&Bsl[(n * 16 + lr) * PK + kr * 32 + lg * 8];
#pragma unroll
            for (int m = 0; m < 2; ++m)
#pragma unroll
                for (int n = 0; n < 4; ++n)
                    acc[m][n] = __builtin_amdgcn_mfma_f32_16x16x32_f16(
                        af[m], bf[n], acc[m][n], 0, 0, 0);
        }
        __syncthreads();
    }

#pragma unroll
    for (int m = 0; m < 2; ++m) {
#pragma unroll
        for (int r = 0; r < 4; ++r) {
            int row = row0 + wr + m * 16 + lg * 4 + r;
            if (row >= M) continue;
#pragma unroll
            for (int n = 0; n < 4; ++n) {
                int col = col0 + n * 16 + lr;
                float v = acc[m][n][r];
                if (RELU) v = fmaxf(v + bias[col], 0.f);
                C[(size_t)row * N + col] = (_Float16)v;
            }
        }
    }
}

// ---------------------------------------------------------------------------
// Gather v2: one wave per node, half4 per lane, lane-groups process GRP edges
// concurrently, 4-step unroll (16 loads in flight per lane-group).
// ---------------------------------------------------------------------------
template <int FO, bool BIASRELU>
__global__ __launch_bounds__(256) void k_gather2(const int* __restrict__ row_ptr,
                                                 const float2* __restrict__ csr,
                                                 const _Float16* __restrict__ H,
                                                 const float* __restrict__ dinv,
                                                 const float* __restrict__ b,
                                                 _Float16* __restrict__ O, int n) {
    constexpr int LPE = FO / 4;     // lanes per edge
    constexpr int GRP = 64 / LPE;   // edges processed in parallel
    int node = blockIdx.x * 4 + (threadIdx.x >> 6);
    int lane = threadIdx.x & 63;
    if (node >= n) return;
    int grp = lane / LPE;
    int cols = (lane % LPE) * 4;

    float ax = 0.f, ay = 0.f, az = 0.f, aw = 0.f;
    int e0 = row_ptr[node], e1 = row_ptr[node + 1];

    for (int e = e0; e < e1; e += 4 * GRP) {
        float nv[4]; half4_t hv[4];
#pragma unroll
        for (int u = 0; u < 4; ++u) {
            int er = e + u * GRP + grp;
            int eg = min(er, e1 - 1);
            float2 c = csr[eg];
            hv[u] = *(const half4_t*)(H + (size_t)__float_as_int(c.x) * FO + cols);
            nv[u] = (er < e1) ? c.y : 0.f;
        }
#pragma unroll
        for (int u = 0; u < 4; ++u) {
            ax += nv[u] * (float)hv[u][0];
            ay += nv[u] * (float)hv[u][1];
            az += nv[u] * (float)hv[u][2];
            aw += nv[u] * (float)hv[u][3];
        }
    }

#pragma unroll
    for (int off = LPE; off < 64; off <<= 1) {
        ax += __shfl_down(ax, off);
        ay += __shfl_down(ay, off);
        az += __shfl_down(az, off);
        aw += __shfl_down(aw, off);
    }

    if (lane < LPE) {
        float di = dinv[node];
        float s = di * di;
        half4_t hs = *(const half4_t*)(H + (size_t)node * FO + cols);
        ax += s * (float)hs[0];
        ay += s * (float)hs[1];
        az += s * (float)hs[2];
        aw += s * (float)hs[3];
        if (BIASRELU) {
            float4 bv = *(const float4*)(b + cols);
            ax = fmaxf(ax + bv.x, 0.f);
            ay = fmaxf(ay + bv.y, 0.f);
            az = fmaxf(az + bv.z, 0.f);
            aw = fmaxf(aw + bv.w, 0.f);
        }
        half4_t o;
        o[0] = (_Float16)ax; o[1] = (_Float16)ay;
        o[2] = (_Float16)az; o[3] = (_Float16)aw;
        *(half4_t*)(O + (size_t)node * FO + cols) = o;
    }
}

// ---------------------------------------------------------------------------
// Fused layer-4 gather + bias + relu + final Linear(256,1). One wave/node.
// ---------------------------------------------------------------------------
__global__ __launch_bounds__(256) void k_gather_final2(const int* __restrict__ row_ptr,
                                                       const float2* __restrict__ csr,
                                                       const _Float16* __restrict__ H,
                                                       const float* __restrict__ dinv,
                                                       const float* __restrict__ b4,
                                                       const float* __restrict__ Wf,
                                                       const float* __restrict__ bf,
                                                       float* __restrict__ out, int n) {
    int node = blockIdx.x * 4 + (threadIdx.x >> 6);
    int lane = threadIdx.x & 63;
    if (node >= n) return;
    int cols = lane * 4;

    float ax = 0.f, ay = 0.f, az = 0.f, aw = 0.f;
    int e0 = row_ptr[node], e1 = row_ptr[node + 1];

    for (int e = e0; e < e1; e += 4) {
        float nv[4]; half4_t hv[4];
#pragma unroll
        for (int u = 0; u < 4; ++u) {
            int er = e + u;
            int eg = min(er, e1 - 1);
            float2 c = csr[eg];
            hv[u] = *(const half4_t*)(H + (size_t)__float_as_int(c.x) * 256 + cols);
            nv[u] = (er < e1) ? c.y : 0.f;
        }
#pragma unroll
        for (int u = 0; u < 4; ++u) {
            ax += nv[u] * (float)hv[u][0];
            ay += nv[u] * (float)hv[u][1];
            az += nv[u] * (float)hv[u][2];
            aw += nv[u] * (float)hv[u][3];
        }
    }

    float di = dinv[node];
    float s = di * di;
    half4_t hs = *(const half4_t*)(H + (size_t)node * 256 + cols);
    float4 bv = *(const float4*)(b4 + cols);
    float4 wv = *(const float4*)(Wf + cols);
    float v = fmaxf(ax + s * (float)hs[0] + bv.x, 0.f) * wv.x
            + fmaxf(ay + s * (float)hs[1] + bv.y, 0.f) * wv.y
            + fmaxf(az + s * (float)hs[2] + bv.z, 0.f) * wv.z
            + fmaxf(aw + s * (float)hs[3] + bv.w, 0.f) * wv.w;
#pragma unroll
    for (int off = 32; off > 0; off >>= 1) v += __shfl_down(v, off);
    if (lane == 0) out[node] = v + bf[0];
}

// ---------------------------------------------------------------------------

extern "C" void kernel_launch(void* const* d_in, const int* in_sizes, int n_in,
                              void* d_out, int out_size, void* d_ws, size_t ws_size,
                              hipStream_t stream) {
    const float* x    = (const float*)d_in[0];
    const int*   eidx = (const int*)d_in[1];
    const float* eatt = (const float*)d_in[2];
    const float* W1 = (const float*)d_in[3];
    const float* b1 = (const float*)d_in[4];
    const float* W2 = (const float*)d_in[5];
    const float* b2 = (const float*)d_in[6];
    const float* W3 = (const float*)d_in[7];
    const float* b3 = (const float*)d_in[8];
    const float* W4 = (const float*)d_in[9];
    const float* b4 = (const float*)d_in[10];
    const float* Wf = (const float*)d_in[11];
    const float* bf = (const float*)d_in[12];

    const int NN = in_sizes[0] / 128;   // 50000
    const int NE = in_sizes[2];         // 800000
    const int* src = eidx;              // edge_index[0]
    const int* dst = eidx + NE;         // edge_index[1]

    // workspace layout (u64 array first for 8B alignment)
    const int Na = (NN + 64) & ~63;
    unsigned long long* packed = (unsigned long long*)d_ws;   // N u64
    float* dinv    = (float*)(packed + Na);     // N floats
    int*   row_ptr = (int*)(dinv + Na);         // N+1 ints
    int*   cnt     = row_ptr + Na;              // N ints
    int*   bsum    = cnt + Na;                  // 64 ints
    int*   boff    = bsum + 64;                 // 64 ints
    int*   slot    = boff + 64;                 // E ints
    float2* csr    = (float2*)(slot + ((NE + 1) & ~1));   // E float2
    _Float16* bufA = (_Float16*)(csr + NE);     // N*256 halves
    _Float16* bufB = bufA + (size_t)NN * 256;   // N*256 halves

    const int nscan = (NN + SCAN_CHUNK - 1) / SCAN_CHUNK;   // 25

    // --- graph preprocessing ---
    k_init<<<(NN + 255) / 256, 256, 0, stream>>>(packed, NN);
    k_count_slot<<<(NE + 255) / 256, 256, 0, stream>>>(dst, eatt, packed, slot, NE);
    k_dinv<<<(NN + 255) / 256, 256, 0, stream>>>(packed, dinv, cnt, NN);
    k_scan_part<<<nscan, 256, 0, stream>>>(cnt, row_ptr, bsum, NN);
    k_scan_mid<<<1, 64, 0, stream>>>(bsum, boff, nscan);
    k_scan_add<<<nscan, 256, 0, stream>>>(row_ptr, boff, NN, NE);
    k_fill<<<(NE + 255) / 256, 256, 0, stream>>>(src, dst, eatt, dinv, row_ptr, slot, csr, NE);

    int gw = (NN + 3) / 4;   // one wave per node, 4 waves per block
    int gx = (NN + 127) / 128;

    // --- L1 (128->64), aggregate AFTER: H1 = x@W1; h1 = relu(gather(H1)+b1)
    gemm_mfma<false, float><<<dim3(gx, 1), 256, 0, stream>>>(x, W1, nullptr, bufB, NN, 128, 64);
    k_gather2<64, true><<<gw, 256, 0, stream>>>(row_ptr, csr, bufB, dinv, b1, bufA, NN);

    // --- L2 (64->128), aggregate BEFORE: g2 = gather(h1); h2 = relu(g2@W2+b2)
    k_gather2<64, false><<<gw, 256, 0, stream>>>(row_ptr, csr, bufA, dinv, nullptr, bufB, NN);
    gemm_mfma<true, _Float16><<<dim3(gx, 2), 256, 0, stream>>>(bufB, W2, b2, bufA, NN, 64, 128);

    // --- L3 (128->256), aggregate BEFORE: g3 = gather(h2); h3 = relu(g3@W3+b3)
    k_gather2<128, false><<<gw, 256, 0, stream>>>(row_ptr, csr, bufA, dinv, nullptr, bufB, NN);
    gemm_mfma<true, _Float16><<<dim3(gx, 4), 256, 0, stream>>>(bufB, W3, b3, bufA, NN, 128, 256);

    // --- L4 (256->256) aggregate AFTER + fused final dot
    gemm_mfma<false, _Float16><<<dim3(gx, 4), 256, 0, stream>>>(bufA, W4, nullptr, bufB, NN, 256, 256);
    k_gather_final2<<<gw, 256, 0, stream>>>(row_ptr, csr, bufB, dinv, b4, Wf, bf,
                                            (float*)d_out, NN);
}